// Round 10
// baseline (327.489 us; speedup 1.0000x reference)
//
#include <hip/hip_runtime.h>
#include <math.h>

#define NN    100000
#define GG    100
#define FIN   12
#define FOUT  32
#define KD    5
#define CC    4
#define EE    1600000
#define ROWS  108          // 9 blocks * 12 features
#define NBF   782          // fwd coarse bins (128 nodes each; last has 96)
#define NBINS 1564         // fwd bins + rev bins
#define NBC   512          // chunks in the coarse build (CHUNK=3125, exact)
#define CHUNK 3125
#define TOTR  (2 * CHUNK)  // records staged per block in k_place
#define NSEG  (NBINS * NBC)   // 800768 = 782 * 1024 exactly
#define SUBMAX 3072        // R20: k_subcsr LDS staging capacity (bin ~2048+4.5sd)

// bf16 helpers: RNE pack, shift unpack. Storage-only precision cut — all
// arithmetic stays fp32. Random-gather working set per direction 2.4 MB
// (< 4 MB per-XCD L2). R19 (32B padded rows) REGRESSED — reverted.
// R21 (cooperative 4-step gather fusion) KILLED THE HARNESS — cooperative
// launch is incompatible with HIP graph capture; reverted to per-step
// dispatches. R22: step 4 folded into k_fused (T4 never materialized) —
// neutral on time but exposed k_fused as latency-bound (barrier-serialized
// stage/FMA phases). R23 (50-node segments, more blocks) REGRESSED: +25%
// lane waste, +18MB fetch — occupancy was the wrong lever. R24: producer/
// consumer wave split (4 FMA waves + 4 stage waves, rows dbuf, 1 barrier/
// phase) — phase time = max(stage, FMA), not sum.
__device__ __forceinline__ unsigned bfr(float f) {
    unsigned u = __float_as_uint(f);
    return (u + 0x7FFFu + ((u >> 16) & 1u)) >> 16;
}
__device__ __forceinline__ unsigned pack2(float a, float b) {
    return bfr(a) | (bfr(b) << 16);
}
#define BLO(u) __uint_as_float((u) << 16)
#define BHI(u) __uint_as_float((u) & 0xFFFF0000u)

// XCD-contiguous chunk remap (R11: contiguous ei/ew reads per XCD).
__device__ __forceinline__ int chunk_of_block(int b) {
    return ((b & 7) << 6) | (b >> 3);      // NBC=512: xcd*64 + seq
}

// ---------------- coarse-bucket CSR build ----------------
// Bin layout: bin_f = dst>>7 in [0,NBF); bin_r = NBF + (src>>7).
// recA (bin-major): .x = nbr | (local_node << 17), .y = edge weight.
// R18: k_place LDS-stages its chunk's records bin-sorted, then streams them
// out with full-line coalesced stores (killed the 4.3x dirty-line-thrash
// write amplification: k_place 46us top-1 -> off top-5).

// P1: per-block LDS histogram -> stores into bin-major hist_g[bin][chunk].
__global__ __launch_bounds__(512) void k_hist(const int* __restrict__ ei,
                                              int* __restrict__ hist_g) {
    __shared__ int hist[NBINS];
    for (int i = threadIdx.x; i < NBINS; i += 512) hist[i] = 0;
    __syncthreads();
    int chunk = chunk_of_block(blockIdx.x);
    int lo = chunk * CHUNK, hi = lo + CHUNK;
    for (int e = lo + threadIdx.x; e < hi; e += 512) {
        int s = ei[e], d = ei[EE + e];
        atomicAdd(&hist[d >> 7], 1);
        atomicAdd(&hist[NBF + (s >> 7)], 1);
    }
    __syncthreads();
    for (int i = threadIdx.x; i < NBINS; i += 512)
        hist_g[i * NBC + chunk] = hist[i];
}

// P2a: block-wise exclusive scan of hist_g; ALSO absorbs the old k_misc
// (R20: weight collapse, out init, bf16-x build — independent work rides
// the 800k-thread grid for free, one fewer dispatch).
__global__ __launch_bounds__(1024) void k_scan1(
        int* __restrict__ g, int* __restrict__ bsum,
        const float* __restrict__ Wz_in, const float* __restrict__ Wh_in,
        float* __restrict__ Wz, float* __restrict__ Wh,
        const float* __restrict__ b_lin, float* __restrict__ out,
        const float* __restrict__ x, uint2* __restrict__ xb) {
    __shared__ int sh[1024];
    int t = threadIdx.x;
    int i = blockIdx.x * 1024 + t;
    int v = g[i];                      // NSEG is an exact multiple of 1024
    sh[t] = v;
    __syncthreads();
    for (int d = 1; d < 1024; d <<= 1) {
        int x2 = sh[t];
        if (t >= d) x2 += sh[t - d];
        __syncthreads();
        sh[t] = x2;
        __syncthreads();
    }
    g[i] = sh[t] - v;
    if (t == 1023) bsum[blockIdx.x] = sh[1023];

    // ---- folded misc work (thread id i spans 0..800767) ----
    if (i < 2 * ROWS * FOUT) {
        int sel = i / (ROWS * FOUT);
        int rem = i - sel * ROWS * FOUT;
        int r = rem / FOUT;
        int f = rem - r * FOUT;
        int b = r / 12;
        int ii = r - b * 12;
        const float* Ws = sel ? Wh_in : Wz_in;
        float vv;
        if (b == 0)
            vv = Ws[(0 * KD + 0) * 44 * 32 + ii * 32 + f] + Ws[(1 * KD + 0) * 44 * 32 + ii * 32 + f];
        else if (b <= 4)
            vv = Ws[(0 * KD + b) * 44 * 32 + ii * 32 + f];
        else
            vv = Ws[(1 * KD + (b - 4)) * 44 * 32 + ii * 32 + f];
        (sel ? Wh : Wz)[r * FOUT + f] = vv;
    }
    int u = i - 2 * ROWS * FOUT;
    if (u >= 0 && u < GG * CC) out[u] = b_lin[u & 3];
    if (i < 3 * NN) {
        int n = i / 3, c = i - n * 3;
        float4 vf = *(const float4*)(x + (size_t)n * FIN + c * 4);
        xb[(size_t)n * 3 + c] = make_uint2(pack2(vf.x, vf.y), pack2(vf.z, vf.w));
    }
}

// P2b: adds block base (in-block reduction of bsum[0..bid) — R20: replaces
// the 1-block k_scan2 dispatch); extracts bucket offsets off[bin];
// terminates off/off_node with 2*EE.
__global__ __launch_bounds__(1024) void k_scan3(int* __restrict__ g,
                                                const int* __restrict__ bsum,
                                                int* __restrict__ off,
                                                int* __restrict__ off_node) {
    __shared__ int sh[1024];
    int t = threadIdx.x;
    sh[t] = (t < blockIdx.x) ? bsum[t] : 0;   // nbScan=782 <= 1024
    __syncthreads();
    for (int d = 512; d > 0; d >>= 1) {
        if (t < d) sh[t] += sh[t + d];
        __syncthreads();
    }
    int base = sh[0];
    int i = blockIdx.x * 1024 + t;
    int v = g[i] + base;
    g[i] = v;
    if ((i & (NBC - 1)) == 0) off[i / NBC] = v;
    if (i == 0) { off[NBINS] = 2 * EE; off_node[2 * NN] = 2 * EE; }
}

// P3: LDS-staged placement. Counts/bases come from the scanned hist_g
// (count = next base - base), so no edge recount. Records are counting-
// sorted into LDS by bin, then streamed out contiguously: every recA line
// is written once, fully, at one instant.
__global__ __launch_bounds__(512) void k_place(const int* __restrict__ ei,
                                               const float* __restrict__ ew,
                                               const int* __restrict__ base_g,
                                               int2* __restrict__ recA) {
    __shared__ int2 ldsrec[TOTR];            // 50 KB
    __shared__ int  lofs[NBINS];             // 6.2 KB (exclusive prefix)
    __shared__ int  cur[NBINS];              // 6.2 KB
    __shared__ int  sbase[NBINS];            // 6.2 KB (global segment bases)
    __shared__ unsigned short binof[TOTR];   // 12.5 KB (bin of LDS slot)
    int* psum = (int*)binof;                 // scan scratch aliases binof (dead then)
    int t = threadIdx.x;
    int chunk = chunk_of_block(blockIdx.x);

    // per-(bin,chunk) counts and global bases from the scanned hist_g
    for (int bin = t; bin < NBINS; bin += 512) {
        int b0 = base_g[bin * NBC + chunk];
        int b1;
        if (chunk < NBC - 1)      b1 = base_g[bin * NBC + chunk + 1];
        else if (bin < NBINS - 1) b1 = base_g[(bin + 1) * NBC];
        else                      b1 = 2 * EE;
        sbase[bin] = b0;
        lofs[bin] = b1 - b0;                 // count; scanned in place below
        cur[bin] = 0;
    }
    __syncthreads();

    // exclusive scan of lofs over NBINS: 4 elems/thread + Hillis-Steele
    int i0 = t * 4;
    int v0 = 0, v1 = 0, v2 = 0, v3 = 0;
    if (i0 + 0 < NBINS) v0 = lofs[i0];
    if (i0 + 1 < NBINS) v1 = lofs[i0 + 1];
    if (i0 + 2 < NBINS) v2 = lofs[i0 + 2];
    if (i0 + 3 < NBINS) v3 = lofs[i0 + 3];
    int s = v0 + v1 + v2 + v3;
    psum[t] = s;
    __syncthreads();
    for (int d = 1; d < 512; d <<= 1) {
        int x = psum[t];
        if (t >= d) x += psum[t - d];
        __syncthreads();
        psum[t] = x;
        __syncthreads();
    }
    int run = psum[t] - s;
    __syncthreads();                         // psum reads done before binof reuse
    if (i0 + 0 < NBINS) { lofs[i0]     = run; run += v0; }
    if (i0 + 1 < NBINS) { lofs[i0 + 1] = run; run += v1; }
    if (i0 + 2 < NBINS) { lofs[i0 + 2] = run; run += v2; }
    if (i0 + 3 < NBINS) { lofs[i0 + 3] = run; run += v3; }
    __syncthreads();

    // place records into LDS, bin-sorted
    int lo = chunk * CHUNK;
    for (int e = lo + t; e < lo + CHUNK; e += 512) {
        int s2 = ei[e], d2 = ei[EE + e];
        float w = ew[e];
        int bf = d2 >> 7;
        int pf = lofs[bf] + atomicAdd(&cur[bf], 1);
        ldsrec[pf] = make_int2(s2 | ((d2 & 127) << 17), __float_as_int(w));
        binof[pf] = (unsigned short)bf;
        int br = NBF + (s2 >> 7);
        int pr = lofs[br] + atomicAdd(&cur[br], 1);
        ldsrec[pr] = make_int2(d2 | ((s2 & 127) << 17), __float_as_int(w));
        binof[pr] = (unsigned short)br;
    }
    __syncthreads();

    // coalesced write-out: slot i -> recA[sbase[bin] + (i - lofs[bin])]
    for (int i = t; i < TOTR; i += 512) {
        int b = binof[i];
        recA[sbase[b] + (i - lofs[b])] = ldsrec[i];
    }
}

// P4: per-bin counting sort by local node -> exact per-node CSR (4B records),
// fused weighted-degree sums -> dinv, and (rev bins) gA = bf16(dinv_out .* x).
// R20: single global read of the recA segment — staged in LDS (SUBMAX), the
// histogram rides the staging pass and the placement pass reads LDS.
__global__ __launch_bounds__(256) void k_subcsr(
        const int* __restrict__ off, const int2* __restrict__ recA,
        const float* __restrict__ x,
        int* __restrict__ off_node, int* __restrict__ rec2,
        float* __restrict__ dinv_in, float* __restrict__ dinv_out,
        uint2* __restrict__ gA) {
    __shared__ int2  seg[SUBMAX];    // 24 KB
    __shared__ int   hist[128];
    __shared__ int   lofs[128];
    __shared__ int   cur[128];
    __shared__ float wsum[128];
    __shared__ float dl[128];
    int b = blockIdx.x;
    int t = threadIdx.x;
    if (t < 128) { hist[t] = 0; wsum[t] = 0.f; }
    __syncthreads();
    int e0 = off[b], e1 = off[b + 1];
    int cnt = e1 - e0;
    bool stg = (cnt <= SUBMAX);
    if (stg) {
        for (int i = t; i < cnt; i += 256) {
            int2 r = recA[e0 + i];
            seg[i] = r;
            int loc = r.x >> 17;
            atomicAdd(&hist[loc], 1);
            atomicAdd(&wsum[loc], __int_as_float(r.y));
        }
    } else {
        for (int i = t; i < cnt; i += 256) {
            int2 r = recA[e0 + i];
            int loc = r.x >> 17;
            atomicAdd(&hist[loc], 1);
            atomicAdd(&wsum[loc], __int_as_float(r.y));
        }
    }
    __syncthreads();
    if (t < 128) lofs[t] = hist[t];
    __syncthreads();
    for (int d = 1; d < 128; d <<= 1) {
        int v = 0;
        if (t < 128 && t >= d) v = lofs[t - d];
        __syncthreads();
        if (t < 128) lofs[t] += v;
        __syncthreads();
    }
    bool rev = b >= NBF;
    int base = (rev ? b - NBF : b) * 128;
    if (t < 128) {
        int ex = lofs[t] - hist[t];      // exclusive
        lofs[t] = ex;
        cur[t] = 0;
        int node = base + t;
        if (node < NN) {
            off_node[(rev ? NN : 0) + node] = e0 + ex;
            float inv = 1.f / wsum[t];
            dl[t] = inv;
            if (rev) dinv_out[node] = inv;
            else     dinv_in[node]  = inv;
        }
    }
    __syncthreads();
    if (stg) {
        for (int i = t; i < cnt; i += 256) {
            int rx = seg[i].x;
            int loc = rx >> 17;
            int pos = e0 + lofs[loc] + atomicAdd(&cur[loc], 1);
            rec2[pos] = rx & 0x1FFFF;
        }
    } else {
        for (int i = t; i < cnt; i += 256) {
            int rx = recA[e0 + i].x;
            int loc = rx >> 17;
            int pos = e0 + lofs[loc] + atomicAdd(&cur[loc], 1);
            rec2[pos] = rx & 0x1FFFF;
        }
    }
    if (rev) {
        __syncthreads();
        for (int i = t; i < 128 * 3; i += 256) {
            int loc = i / 3, cc = i - loc * 3;
            int node = base + loc;
            if (node < NN) {
                float4 v = *(const float4*)(x + (size_t)node * FIN + cc * 4);
                float sc = dl[loc];
                gA[(size_t)node * 3 + cc] =
                    make_uint2(pack2(v.x * sc, v.y * sc), pack2(v.z * sc, v.w * sc));
            }
        }
    }
}

// ---------------- diffusion gather ----------------
// bf16 rows (12 halves = 24B): random-read working set 2.4 MB/direction,
// fully resident in a 4 MB XCD L2. All arithmetic fp32; rounding only at
// stores. XCD direction split (0-3 fwd, 4-7 rev), rec2 LDS staging (R15),
// LREC=2048 (R16), 8-wide unrolled edge loop. R22: only steps 1-3 run here;
// step 4 is computed inside k_fused.
#define LREC 2048
__global__ __launch_bounds__(256) void k_gather(
        const int* __restrict__ off_node, const int* __restrict__ rec2,
        const uint2* __restrict__ gIn, const uint2* __restrict__ hIn,
        const uint2* __restrict__ prevF, const uint2* __restrict__ prevR,
        const float* __restrict__ dinv_in, const float* __restrict__ dinv_out,
        uint2* __restrict__ outF, uint2* __restrict__ outR,
        uint2* __restrict__ gOut, float c) {
    __shared__ int lrec[LREC];
    int xcd = blockIdx.x & 7;
    int grp = blockIdx.x >> 3;             // 0..292
    bool rev = xcd >= 4;
    int dbase = rev ? NN : 0;
    int ub = (grp * 4 + (xcd & 3)) * 256;  // block's first lin
    int lin = ub + threadIdx.x;

    // block's contiguous rec2 window
    int u1 = ub + 255; if (u1 > 3 * NN - 1) u1 = 3 * NN - 1;
    int node0 = ub / 3, node1 = u1 / 3;
    int w0 = off_node[dbase + node0];
    int w1 = off_node[dbase + node1 + 1];
    int wn = w1 - w0;
    bool useLds = (wn <= LREC);
    if (useLds) {
        for (int i = threadIdx.x; i < wn; i += 256) lrec[i] = rec2[w0 + i];
    }
    __syncthreads();

    if (lin < 3 * NN) {
        int node = lin / 3;
        int ch = lin - node * 3;
        int i0 = dbase + node;
        int e0 = off_node[i0], e1 = off_node[i0 + 1];
        const uint2* in = rev ? hIn : gIn;

        float ax = 0.f, ay = 0.f, az = 0.f, aw = 0.f;
        float bx = 0.f, by = 0.f, bz = 0.f, bw = 0.f;
        if (useLds) {
            int a0 = e0 - w0, a1 = e1 - w0;
            int e = a0;
            for (; e + 7 < a1; e += 8) {
                int n0 = lrec[e],     n1 = lrec[e + 1], n2 = lrec[e + 2], n3 = lrec[e + 3];
                int n4 = lrec[e + 4], n5 = lrec[e + 5], n6 = lrec[e + 6], n7 = lrec[e + 7];
                uint2 v0 = in[(size_t)n0 * 3 + ch];
                uint2 v1 = in[(size_t)n1 * 3 + ch];
                uint2 v2 = in[(size_t)n2 * 3 + ch];
                uint2 v3 = in[(size_t)n3 * 3 + ch];
                uint2 v4 = in[(size_t)n4 * 3 + ch];
                uint2 v5 = in[(size_t)n5 * 3 + ch];
                uint2 v6 = in[(size_t)n6 * 3 + ch];
                uint2 v7 = in[(size_t)n7 * 3 + ch];
                ax += BLO(v0.x); ay += BHI(v0.x); az += BLO(v0.y); aw += BHI(v0.y);
                bx += BLO(v1.x); by += BHI(v1.x); bz += BLO(v1.y); bw += BHI(v1.y);
                ax += BLO(v2.x); ay += BHI(v2.x); az += BLO(v2.y); aw += BHI(v2.y);
                bx += BLO(v3.x); by += BHI(v3.x); bz += BLO(v3.y); bw += BHI(v3.y);
                ax += BLO(v4.x); ay += BHI(v4.x); az += BLO(v4.y); aw += BHI(v4.y);
                bx += BLO(v5.x); by += BHI(v5.x); bz += BLO(v5.y); bw += BHI(v5.y);
                ax += BLO(v6.x); ay += BHI(v6.x); az += BLO(v6.y); aw += BHI(v6.y);
                bx += BLO(v7.x); by += BHI(v7.x); bz += BLO(v7.y); bw += BHI(v7.y);
            }
            for (; e < a1; ++e) {
                int n0 = lrec[e];
                uint2 v0 = in[(size_t)n0 * 3 + ch];
                ax += BLO(v0.x); ay += BHI(v0.x); az += BLO(v0.y); aw += BHI(v0.y);
            }
        } else {
            for (int e = e0; e < e1; ++e) {
                int n0 = rec2[e];
                uint2 v0 = in[(size_t)n0 * 3 + ch];
                ax += BLO(v0.x); ay += BHI(v0.x); az += BLO(v0.y); aw += BHI(v0.y);
            }
        }
        ax += bx; ay += by; az += bz; aw += bw;

        float sc = rev ? c * dinv_in[node] : c;
        ax *= sc; ay *= sc; az *= sc; aw *= sc;

        size_t o = (size_t)node * 3 + ch;
        if (prevF) {
            uint2 p = (rev ? prevR : prevF)[o];
            ax -= BLO(p.x); ay -= BHI(p.x); az -= BLO(p.y); aw -= BHI(p.y);
        }
        (rev ? outR : outF)[o] = make_uint2(pack2(ax, ay), pack2(az, aw));
        if (!rev && gOut) {
            float g = dinv_out[node];
            gOut[o] = make_uint2(pack2(g * ax, g * ay), pack2(g * az, g * aw));
        }
    }
}

// ---------------- epilogue ----------------

// R24: producer/consumer wave specialization. 512 threads over 250-node
// segments (400 blocks, whole grid resident): waves 0-3 = consumers (FMA
// only; each lane owns nodes lane/+64/+128/+192 x 8 features), waves 4-7 =
// producers (stage tile b+1 into the double-buffered rows while consumers
// FMA tile b). One barrier per phase => phase time = max(stage, FMA), not
// sum. T4o (b==4) / T4i (b==8) gathered in-kernel (R22) by producers, with
// an frec fill (all threads) + internal barrier preceding.
#define SEGN  250
#define NSEGB 4            // segments per graph
#define FREC  5120
__global__ __launch_bounds__(512) void k_fused(
        const float* __restrict__ x, const uint2* __restrict__ TS2,
        const int* __restrict__ off_node, const int* __restrict__ rec2,
        const uint2* __restrict__ gB, const float* __restrict__ dinv_in,
        const float* __restrict__ Wz, const float* __restrict__ Wh,
        const float* __restrict__ bz, const float* __restrict__ bh,
        const float* __restrict__ Wlin, float* __restrict__ out) {
    __shared__ float rows[2][256][13];   // 26.6 KB (double-buffered tiles)
    __shared__ float red[512 * CC];      // 8 KB
    __shared__ int   frec[FREC];         // 20.5 KB (gather-phase rec2 window)
    int g = blockIdx.x >> 2;
    int seg = blockIdx.x & 3;
    int base = g * 1000 + seg * SEGN;
    int tid = threadIdx.x;
    int lane = tid & 63;
    int wave = tid >> 6;
    bool cons = wave < 4;                // consumer waves
    int pid = tid - 256;                 // producer thread id (0..255)
    int f0 = __builtin_amdgcn_readfirstlane((wave & 3) * 8);

    const uint2* T2o = TS2 + (size_t)1 * NN * 3;
    const uint2* T2i = TS2 + (size_t)5 * NN * 3;
    const uint2* T3i = TS2 + (size_t)6 * NN * 3;

    float az0[8], ah0[8], az1[8], ah1[8], az2[8], ah2[8], az3[8], ah3[8];
#pragma unroll
    for (int fi = 0; fi < 8; ++fi) {
        float vz = bz[f0 + fi], vh = bh[f0 + fi];
        az0[fi] = vz; ah0[fi] = vh; az1[fi] = vz; ah1[fi] = vh;
        az2[fi] = vz; ah2[fi] = vh; az3[fi] = vz; ah3[fi] = vh;
    }

    // prologue: producers stage tile 0 (x, exact fp32) into rows[0]
    if (!cons) {
        const float* src = x + (size_t)base * FIN;
        for (int q = pid; q < 750; q += 256) {   // 250*12 floats = 750 float4
            float4 v = *(const float4*)(src + q * 4);
            int e = q * 4;
            int n0 = e / 12,       i0 = e - n0 * 12;       rows[0][n0][i0] = v.x;
            int n1 = (e + 1) / 12, i1 = (e + 1) - n1 * 12; rows[0][n1][i1] = v.y;
            int n2 = (e + 2) / 12, i2 = (e + 2) - n2 * 12; rows[0][n2][i2] = v.z;
            int n3 = (e + 3) / 12, i3 = (e + 3) - n3 * 12; rows[0][n3][i3] = v.w;
        }
    }
    __syncthreads();

    for (int b = 0; b < 9; ++b) {
        int nb = b + 1;
        int cur = b & 1, nxt = nb & 1;
        if (nb == 4 || nb == 8) {
            // fused Chebyshev step 4 staging (fwd at nb==4, rev at nb==8)
            bool revd = (nb == 8);
            int dbase = revd ? NN : 0;
            int w0 = off_node[dbase + base];
            int w1 = off_node[dbase + base + SEGN];
            int wn = w1 - w0;
            bool useLds = (wn <= FREC);
            if (useLds) {
                for (int i = tid; i < wn; i += 512) frec[i] = rec2[w0 + i];
            }
            __syncthreads();             // frec ready (short, coalesced fill)
            if (!cons) {
                const uint2* gin  = revd ? T3i : gB;
                const uint2* prev = revd ? T2i : T2o;
                for (int item = pid; item < 750; item += 256) {
                    int n = item / 3, cc = item - n * 3;
                    int node = base + n;
                    int e0 = off_node[dbase + node], e1 = off_node[dbase + node + 1];
                    float ax = 0.f, ay = 0.f, az = 0.f, aw = 0.f;
                    float bx2 = 0.f, by2 = 0.f, bz2 = 0.f, bw2 = 0.f;
                    if (useLds) {
                        int a0 = e0 - w0, a1 = e1 - w0;
                        int e = a0;
                        for (; e + 7 < a1; e += 8) {
                            int n0 = frec[e],     n1 = frec[e + 1], n2 = frec[e + 2], n3 = frec[e + 3];
                            int n4 = frec[e + 4], n5 = frec[e + 5], n6 = frec[e + 6], n7 = frec[e + 7];
                            uint2 v0 = gin[(size_t)n0 * 3 + cc];
                            uint2 v1 = gin[(size_t)n1 * 3 + cc];
                            uint2 v2 = gin[(size_t)n2 * 3 + cc];
                            uint2 v3 = gin[(size_t)n3 * 3 + cc];
                            uint2 v4 = gin[(size_t)n4 * 3 + cc];
                            uint2 v5 = gin[(size_t)n5 * 3 + cc];
                            uint2 v6 = gin[(size_t)n6 * 3 + cc];
                            uint2 v7 = gin[(size_t)n7 * 3 + cc];
                            ax += BLO(v0.x); ay += BHI(v0.x); az += BLO(v0.y); aw += BHI(v0.y);
                            bx2 += BLO(v1.x); by2 += BHI(v1.x); bz2 += BLO(v1.y); bw2 += BHI(v1.y);
                            ax += BLO(v2.x); ay += BHI(v2.x); az += BLO(v2.y); aw += BHI(v2.y);
                            bx2 += BLO(v3.x); by2 += BHI(v3.x); bz2 += BLO(v3.y); bw2 += BHI(v3.y);
                            ax += BLO(v4.x); ay += BHI(v4.x); az += BLO(v4.y); aw += BHI(v4.y);
                            bx2 += BLO(v5.x); by2 += BHI(v5.x); bz2 += BLO(v5.y); bw2 += BHI(v5.y);
                            ax += BLO(v6.x); ay += BHI(v6.x); az += BLO(v6.y); aw += BHI(v6.y);
                            bx2 += BLO(v7.x); by2 += BHI(v7.x); bz2 += BLO(v7.y); bw2 += BHI(v7.y);
                        }
                        for (; e < a1; ++e) {
                            uint2 v = gin[(size_t)frec[e] * 3 + cc];
                            ax += BLO(v.x); ay += BHI(v.x); az += BLO(v.y); aw += BHI(v.y);
                        }
                    } else {
                        for (int e = e0; e < e1; ++e) {
                            uint2 v = gin[(size_t)rec2[e] * 3 + cc];
                            ax += BLO(v.x); ay += BHI(v.x); az += BLO(v.y); aw += BHI(v.y);
                        }
                    }
                    ax += bx2; ay += by2; az += bz2; aw += bw2;
                    float sc = revd ? 2.f * dinv_in[node] : 2.f;
                    uint2 p = prev[(size_t)node * 3 + cc];
                    rows[nxt][n][cc * 4 + 0] = ax * sc - BLO(p.x);
                    rows[nxt][n][cc * 4 + 1] = ay * sc - BHI(p.x);
                    rows[nxt][n][cc * 4 + 2] = az * sc - BLO(p.y);
                    rows[nxt][n][cc * 4 + 3] = aw * sc - BHI(p.y);
                }
            }
        } else if (nb <= 8) {
            if (!cons) {
                const uint2* Tb = TS2 + (size_t)(nb - 1) * NN * 3;
                for (int item = pid; item < 750; item += 256) {
                    int n = item / 3, cc = item - n * 3;
                    uint2 v = Tb[(size_t)(base + n) * 3 + cc];
                    rows[nxt][n][cc * 4 + 0] = BLO(v.x);
                    rows[nxt][n][cc * 4 + 1] = BHI(v.x);
                    rows[nxt][n][cc * 4 + 2] = BLO(v.y);
                    rows[nxt][n][cc * 4 + 3] = BHI(v.y);
                }
            }
        }
        if (cons) {
            const float* wzr = Wz + b * 12 * FOUT + f0;
            const float* whr = Wh + b * 12 * FOUT + f0;
#pragma unroll
            for (int i = 0; i < FIN; ++i) {
                float v0 = rows[cur][lane][i];
                float v1 = rows[cur][lane + 64][i];
                float v2 = rows[cur][lane + 128][i];
                float v3 = rows[cur][lane + 192][i];   // junk for lane>=58; masked later
#pragma unroll
                for (int fi = 0; fi < 8; ++fi) {
                    float wz = wzr[i * FOUT + fi];     // scalar loads (wave-uniform)
                    float wh = whr[i * FOUT + fi];
                    az0[fi] = fmaf(v0, wz, az0[fi]); ah0[fi] = fmaf(v0, wh, ah0[fi]);
                    az1[fi] = fmaf(v1, wz, az1[fi]); ah1[fi] = fmaf(v1, wh, ah1[fi]);
                    az2[fi] = fmaf(v2, wz, az2[fi]); ah2[fi] = fmaf(v2, wh, ah2[fi]);
                    az3[fi] = fmaf(v3, wz, az3[fi]); ah3[fi] = fmaf(v3, wh, ah3[fi]);
                }
            }
        }
        __syncthreads();
    }

    float o[CC] = {0.f, 0.f, 0.f, 0.f};
    if (cons) {
        auto actacc = [&](const float* azp, const float* ahp) {
#pragma unroll
            for (int fi = 0; fi < 8; ++fi) {
                float z = 1.f / (1.f + __expf(-azp[fi]));
                float e2 = __expf(2.f * ahp[fi]);
                float th = 1.f - 2.f / (e2 + 1.f);
                float hv = fmaxf((1.f - z) * th, 0.f);
#pragma unroll
                for (int c = 0; c < CC; ++c) o[c] = fmaf(hv, Wlin[(f0 + fi) * 4 + c], o[c]);
            }
        };
        actacc(az0, ah0);                 // node lane        (<250 always)
        actacc(az1, ah1);                 // node lane+64
        actacc(az2, ah2);                 // node lane+128
        if (lane < 58) actacc(az3, ah3);  // node lane+192 valid iff lane<58
    }

#pragma unroll
    for (int c = 0; c < CC; ++c) red[tid * CC + c] = o[c];
    __syncthreads();
    for (int st = 256; st > 0; st >>= 1) {
        if (tid < st) {
#pragma unroll
            for (int c = 0; c < CC; ++c) red[tid * CC + c] += red[(tid + st) * CC + c];
        }
        __syncthreads();
    }
    if (tid == 0) {
#pragma unroll
        for (int c = 0; c < CC; ++c) atomicAdd(out + g * CC + c, red[c] * 0.001f);
    }
}

// ---------------- launch ----------------

extern "C" void kernel_launch(void* const* d_in, const int* in_sizes, int n_in,
                              void* d_out, int out_size, void* d_ws, size_t ws_size,
                              hipStream_t stream) {
    const float* x     = (const float*)d_in[0];
    const int*   ei    = (const int*)d_in[1];
    const float* ew    = (const float*)d_in[2];
    // d_in[3] (batch) unused: graphs are exactly 1000 contiguous nodes
    const float* W_z   = (const float*)d_in[4];
    const float* b_z   = (const float*)d_in[5];
    // d_in[6], d_in[7] (W_r, b_r) unused: R only multiplies the zero hidden state
    const float* W_h   = (const float*)d_in[8];
    const float* b_h   = (const float*)d_in[9];
    const float* W_lin = (const float*)d_in[10];
    const float* b_lin = (const float*)d_in[11];
    float* out = (float*)d_out;

    // ---- workspace layout (~48 MB) ----
    // [rec2 12.8MB][TSb 19.2MB bf16 basis | recA 25.6MB spans TSb + 6.4MB pad]
    // [gA][gB][xb] bf16 2.4MB each, placed AFTER recA's span (k_subcsr writes
    // gA while recA is still live) [dinv][W][off][off_node]
    int*   rec2     = (int*)d_ws;                       // 2*EE ints
    unsigned* TSb   = (unsigned*)(rec2 + 2 * (size_t)EE);  // 8 * NN*6 uints (bf16 rows)
    int2*  recA     = (int2*)TSb;                       // ALIAS: 2*EE int2, dead before gather 1
    int*   hist_g   = rec2;                             // ALIAS: NSEG ints, dead before k_subcsr writes rec2
    int*   bsumS    = rec2 + NSEG;                      // ALIAS: 782 ints
    unsigned* gAu   = TSb + (size_t)8 * NN * 6 + 1600000;  // past recA span (pad 6.4MB)
    unsigned* gBu   = gAu + (size_t)NN * 6;
    unsigned* xbu   = gBu + (size_t)NN * 6;
    float* dinv_in  = (float*)(xbu + (size_t)NN * 6);   // N
    float* dinv_out = dinv_in + NN;                     // N
    float* Wz       = dinv_out + NN;                    // 108*32
    float* Wh       = Wz + ROWS * FOUT;                 // 108*32
    int*   off      = (int*)(Wh + ROWS * FOUT);         // NBINS+1
    int*   off_node = off + NBINS + 1;                  // 2N+1

    uint2* TS2 = (uint2*)TSb;
    uint2* T1o = TS2 + (size_t)0 * NN * 3;
    uint2* T2o = TS2 + (size_t)1 * NN * 3;
    uint2* T3o = TS2 + (size_t)2 * NN * 3;
    uint2* T1i = TS2 + (size_t)4 * NN * 3;
    uint2* T2i = TS2 + (size_t)5 * NN * 3;
    uint2* T3i = TS2 + (size_t)6 * NN * 3;
    uint2* gA = (uint2*)gAu;
    uint2* gB = (uint2*)gBu;
    uint2* xb = (uint2*)xbu;

    dim3 B(256);
    int nbG = 2344;                            // 293 * 8 — exact for the XCD swizzle
    int nbScan = NSEG / 1024;                  // 782, exact

    k_hist<<<NBC, 512, 0, stream>>>(ei, hist_g);
    k_scan1<<<nbScan, 1024, 0, stream>>>(hist_g, bsumS, W_z, W_h, Wz, Wh, b_lin, out, x, xb);
    k_scan3<<<nbScan, 1024, 0, stream>>>(hist_g, bsumS, off, off_node);
    k_place<<<NBC, 512, 0, stream>>>(ei, ew, hist_g, recA);
    k_subcsr<<<NBINS, B, 0, stream>>>(off, recA, x, off_node, rec2, dinv_in, dinv_out, gA);

    // Chebyshev diffusion basis steps 1-3 (bf16 storage, fp32 math); step 4
    // is fused into the epilogue (R22/R24).
    k_gather<<<nbG, B, 0, stream>>>(off_node, rec2, gA, xb,  nullptr, nullptr, dinv_in, dinv_out, T1o, T1i, gB, 1.f);
    k_gather<<<nbG, B, 0, stream>>>(off_node, rec2, gB, T1i, xb,      xb,      dinv_in, dinv_out, T2o, T2i, gA, 2.f);
    k_gather<<<nbG, B, 0, stream>>>(off_node, rec2, gA, T2i, T1o,     T1i,     dinv_in, dinv_out, T3o, T3i, gB, 2.f);

    k_fused<<<NSEGB * GG, 512, 0, stream>>>(x, TS2, off_node, rec2, gB, dinv_in,
                                            Wz, Wh, b_z, b_h, W_lin, out);
}

// Round 11
// 286.094 us; speedup vs baseline: 1.1447x; 1.1447x over previous
//
#include <hip/hip_runtime.h>
#include <math.h>

#define NN    100000
#define GG    100
#define FIN   12
#define FOUT  32
#define KD    5
#define CC    4
#define EE    1600000
#define ROWS  108          // 9 blocks * 12 features
#define NBF   782          // fwd coarse bins (128 nodes each; last has 96)
#define NBINS 1564         // fwd bins + rev bins
#define NBC   512          // chunks in the coarse build (CHUNK=3125, exact)
#define CHUNK 3125
#define TOTR  (2 * CHUNK)  // records staged per block in k_place
#define NSEG  (NBINS * NBC)   // 800768 = 782 * 1024 exactly
#define SUBMAX 3072        // R20: k_subcsr LDS staging capacity (bin ~2048+4.5sd)

// bf16 helpers: RNE pack, shift unpack. Storage-only precision cut — all
// arithmetic stays fp32. Random-gather working set per direction 2.4 MB
// (< 4 MB per-XCD L2). R19 (32B padded rows) REGRESSED — reverted.
// R21 (cooperative 4-step gather fusion) KILLED THE HARNESS — cooperative
// launch is incompatible with HIP graph capture; reverted to per-step
// dispatches. R22 (step-4 fold into k_fused): neutral. R23 (50-node
// segments): REGRESSED (+25% lane waste, +18MB fetch). R24 (producer/
// consumer wave split, 55KB LDS): REGRESSED (2 blocks/CU, 17% occupancy).
// R25: locked at the R7 structure — measured best 283.0 us.
__device__ __forceinline__ unsigned bfr(float f) {
    unsigned u = __float_as_uint(f);
    return (u + 0x7FFFu + ((u >> 16) & 1u)) >> 16;
}
__device__ __forceinline__ unsigned pack2(float a, float b) {
    return bfr(a) | (bfr(b) << 16);
}
#define BLO(u) __uint_as_float((u) << 16)
#define BHI(u) __uint_as_float((u) & 0xFFFF0000u)

// XCD-contiguous chunk remap (R11: contiguous ei/ew reads per XCD).
__device__ __forceinline__ int chunk_of_block(int b) {
    return ((b & 7) << 6) | (b >> 3);      // NBC=512: xcd*64 + seq
}

// ---------------- coarse-bucket CSR build ----------------
// Bin layout: bin_f = dst>>7 in [0,NBF); bin_r = NBF + (src>>7).
// recA (bin-major): .x = nbr | (local_node << 17), .y = edge weight.
// R18: k_place LDS-stages its chunk's records bin-sorted, then streams them
// out with full-line coalesced stores (killed the 4.3x dirty-line-thrash
// write amplification: k_place 46us top-1 -> off top-5).

// P1: per-block LDS histogram -> stores into bin-major hist_g[bin][chunk].
__global__ __launch_bounds__(512) void k_hist(const int* __restrict__ ei,
                                              int* __restrict__ hist_g) {
    __shared__ int hist[NBINS];
    for (int i = threadIdx.x; i < NBINS; i += 512) hist[i] = 0;
    __syncthreads();
    int chunk = chunk_of_block(blockIdx.x);
    int lo = chunk * CHUNK, hi = lo + CHUNK;
    for (int e = lo + threadIdx.x; e < hi; e += 512) {
        int s = ei[e], d = ei[EE + e];
        atomicAdd(&hist[d >> 7], 1);
        atomicAdd(&hist[NBF + (s >> 7)], 1);
    }
    __syncthreads();
    for (int i = threadIdx.x; i < NBINS; i += 512)
        hist_g[i * NBC + chunk] = hist[i];
}

// P2a: block-wise exclusive scan of hist_g; ALSO absorbs the old k_misc
// (R20: weight collapse, out init, bf16-x build — independent work rides
// the 800k-thread grid for free, one fewer dispatch).
__global__ __launch_bounds__(1024) void k_scan1(
        int* __restrict__ g, int* __restrict__ bsum,
        const float* __restrict__ Wz_in, const float* __restrict__ Wh_in,
        float* __restrict__ Wz, float* __restrict__ Wh,
        const float* __restrict__ b_lin, float* __restrict__ out,
        const float* __restrict__ x, uint2* __restrict__ xb) {
    __shared__ int sh[1024];
    int t = threadIdx.x;
    int i = blockIdx.x * 1024 + t;
    int v = g[i];                      // NSEG is an exact multiple of 1024
    sh[t] = v;
    __syncthreads();
    for (int d = 1; d < 1024; d <<= 1) {
        int x2 = sh[t];
        if (t >= d) x2 += sh[t - d];
        __syncthreads();
        sh[t] = x2;
        __syncthreads();
    }
    g[i] = sh[t] - v;
    if (t == 1023) bsum[blockIdx.x] = sh[1023];

    // ---- folded misc work (thread id i spans 0..800767) ----
    if (i < 2 * ROWS * FOUT) {
        int sel = i / (ROWS * FOUT);
        int rem = i - sel * ROWS * FOUT;
        int r = rem / FOUT;
        int f = rem - r * FOUT;
        int b = r / 12;
        int ii = r - b * 12;
        const float* Ws = sel ? Wh_in : Wz_in;
        float vv;
        if (b == 0)
            vv = Ws[(0 * KD + 0) * 44 * 32 + ii * 32 + f] + Ws[(1 * KD + 0) * 44 * 32 + ii * 32 + f];
        else if (b <= 4)
            vv = Ws[(0 * KD + b) * 44 * 32 + ii * 32 + f];
        else
            vv = Ws[(1 * KD + (b - 4)) * 44 * 32 + ii * 32 + f];
        (sel ? Wh : Wz)[r * FOUT + f] = vv;
    }
    int u = i - 2 * ROWS * FOUT;
    if (u >= 0 && u < GG * CC) out[u] = b_lin[u & 3];
    if (i < 3 * NN) {
        int n = i / 3, c = i - n * 3;
        float4 vf = *(const float4*)(x + (size_t)n * FIN + c * 4);
        xb[(size_t)n * 3 + c] = make_uint2(pack2(vf.x, vf.y), pack2(vf.z, vf.w));
    }
}

// P2b: adds block base (in-block reduction of bsum[0..bid) — R20: replaces
// the 1-block k_scan2 dispatch); extracts bucket offsets off[bin];
// terminates off/off_node with 2*EE.
__global__ __launch_bounds__(1024) void k_scan3(int* __restrict__ g,
                                                const int* __restrict__ bsum,
                                                int* __restrict__ off,
                                                int* __restrict__ off_node) {
    __shared__ int sh[1024];
    int t = threadIdx.x;
    sh[t] = (t < blockIdx.x) ? bsum[t] : 0;   // nbScan=782 <= 1024
    __syncthreads();
    for (int d = 512; d > 0; d >>= 1) {
        if (t < d) sh[t] += sh[t + d];
        __syncthreads();
    }
    int base = sh[0];
    int i = blockIdx.x * 1024 + t;
    int v = g[i] + base;
    g[i] = v;
    if ((i & (NBC - 1)) == 0) off[i / NBC] = v;
    if (i == 0) { off[NBINS] = 2 * EE; off_node[2 * NN] = 2 * EE; }
}

// P3: LDS-staged placement. Counts/bases come from the scanned hist_g
// (count = next base - base), so no edge recount. Records are counting-
// sorted into LDS by bin, then streamed out contiguously: every recA line
// is written once, fully, at one instant.
__global__ __launch_bounds__(512) void k_place(const int* __restrict__ ei,
                                               const float* __restrict__ ew,
                                               const int* __restrict__ base_g,
                                               int2* __restrict__ recA) {
    __shared__ int2 ldsrec[TOTR];            // 50 KB
    __shared__ int  lofs[NBINS];             // 6.2 KB (exclusive prefix)
    __shared__ int  cur[NBINS];              // 6.2 KB
    __shared__ int  sbase[NBINS];            // 6.2 KB (global segment bases)
    __shared__ unsigned short binof[TOTR];   // 12.5 KB (bin of LDS slot)
    int* psum = (int*)binof;                 // scan scratch aliases binof (dead then)
    int t = threadIdx.x;
    int chunk = chunk_of_block(blockIdx.x);

    // per-(bin,chunk) counts and global bases from the scanned hist_g
    for (int bin = t; bin < NBINS; bin += 512) {
        int b0 = base_g[bin * NBC + chunk];
        int b1;
        if (chunk < NBC - 1)      b1 = base_g[bin * NBC + chunk + 1];
        else if (bin < NBINS - 1) b1 = base_g[(bin + 1) * NBC];
        else                      b1 = 2 * EE;
        sbase[bin] = b0;
        lofs[bin] = b1 - b0;                 // count; scanned in place below
        cur[bin] = 0;
    }
    __syncthreads();

    // exclusive scan of lofs over NBINS: 4 elems/thread + Hillis-Steele
    int i0 = t * 4;
    int v0 = 0, v1 = 0, v2 = 0, v3 = 0;
    if (i0 + 0 < NBINS) v0 = lofs[i0];
    if (i0 + 1 < NBINS) v1 = lofs[i0 + 1];
    if (i0 + 2 < NBINS) v2 = lofs[i0 + 2];
    if (i0 + 3 < NBINS) v3 = lofs[i0 + 3];
    int s = v0 + v1 + v2 + v3;
    psum[t] = s;
    __syncthreads();
    for (int d = 1; d < 512; d <<= 1) {
        int x = psum[t];
        if (t >= d) x += psum[t - d];
        __syncthreads();
        psum[t] = x;
        __syncthreads();
    }
    int run = psum[t] - s;
    __syncthreads();                         // psum reads done before binof reuse
    if (i0 + 0 < NBINS) { lofs[i0]     = run; run += v0; }
    if (i0 + 1 < NBINS) { lofs[i0 + 1] = run; run += v1; }
    if (i0 + 2 < NBINS) { lofs[i0 + 2] = run; run += v2; }
    if (i0 + 3 < NBINS) { lofs[i0 + 3] = run; run += v3; }
    __syncthreads();

    // place records into LDS, bin-sorted
    int lo = chunk * CHUNK;
    for (int e = lo + t; e < lo + CHUNK; e += 512) {
        int s2 = ei[e], d2 = ei[EE + e];
        float w = ew[e];
        int bf = d2 >> 7;
        int pf = lofs[bf] + atomicAdd(&cur[bf], 1);
        ldsrec[pf] = make_int2(s2 | ((d2 & 127) << 17), __float_as_int(w));
        binof[pf] = (unsigned short)bf;
        int br = NBF + (s2 >> 7);
        int pr = lofs[br] + atomicAdd(&cur[br], 1);
        ldsrec[pr] = make_int2(d2 | ((s2 & 127) << 17), __float_as_int(w));
        binof[pr] = (unsigned short)br;
    }
    __syncthreads();

    // coalesced write-out: slot i -> recA[sbase[bin] + (i - lofs[bin])]
    for (int i = t; i < TOTR; i += 512) {
        int b = binof[i];
        recA[sbase[b] + (i - lofs[b])] = ldsrec[i];
    }
}

// P4: per-bin counting sort by local node -> exact per-node CSR (4B records),
// fused weighted-degree sums -> dinv, and (rev bins) gA = bf16(dinv_out .* x).
// R20: single global read of the recA segment — staged in LDS (SUBMAX), the
// histogram rides the staging pass and the placement pass reads LDS.
__global__ __launch_bounds__(256) void k_subcsr(
        const int* __restrict__ off, const int2* __restrict__ recA,
        const float* __restrict__ x,
        int* __restrict__ off_node, int* __restrict__ rec2,
        float* __restrict__ dinv_in, float* __restrict__ dinv_out,
        uint2* __restrict__ gA) {
    __shared__ int2  seg[SUBMAX];    // 24 KB
    __shared__ int   hist[128];
    __shared__ int   lofs[128];
    __shared__ int   cur[128];
    __shared__ float wsum[128];
    __shared__ float dl[128];
    int b = blockIdx.x;
    int t = threadIdx.x;
    if (t < 128) { hist[t] = 0; wsum[t] = 0.f; }
    __syncthreads();
    int e0 = off[b], e1 = off[b + 1];
    int cnt = e1 - e0;
    bool stg = (cnt <= SUBMAX);
    if (stg) {
        for (int i = t; i < cnt; i += 256) {
            int2 r = recA[e0 + i];
            seg[i] = r;
            int loc = r.x >> 17;
            atomicAdd(&hist[loc], 1);
            atomicAdd(&wsum[loc], __int_as_float(r.y));
        }
    } else {
        for (int i = t; i < cnt; i += 256) {
            int2 r = recA[e0 + i];
            int loc = r.x >> 17;
            atomicAdd(&hist[loc], 1);
            atomicAdd(&wsum[loc], __int_as_float(r.y));
        }
    }
    __syncthreads();
    if (t < 128) lofs[t] = hist[t];
    __syncthreads();
    for (int d = 1; d < 128; d <<= 1) {
        int v = 0;
        if (t < 128 && t >= d) v = lofs[t - d];
        __syncthreads();
        if (t < 128) lofs[t] += v;
        __syncthreads();
    }
    bool rev = b >= NBF;
    int base = (rev ? b - NBF : b) * 128;
    if (t < 128) {
        int ex = lofs[t] - hist[t];      // exclusive
        lofs[t] = ex;
        cur[t] = 0;
        int node = base + t;
        if (node < NN) {
            off_node[(rev ? NN : 0) + node] = e0 + ex;
            float inv = 1.f / wsum[t];
            dl[t] = inv;
            if (rev) dinv_out[node] = inv;
            else     dinv_in[node]  = inv;
        }
    }
    __syncthreads();
    if (stg) {
        for (int i = t; i < cnt; i += 256) {
            int rx = seg[i].x;
            int loc = rx >> 17;
            int pos = e0 + lofs[loc] + atomicAdd(&cur[loc], 1);
            rec2[pos] = rx & 0x1FFFF;
        }
    } else {
        for (int i = t; i < cnt; i += 256) {
            int rx = recA[e0 + i].x;
            int loc = rx >> 17;
            int pos = e0 + lofs[loc] + atomicAdd(&cur[loc], 1);
            rec2[pos] = rx & 0x1FFFF;
        }
    }
    if (rev) {
        __syncthreads();
        for (int i = t; i < 128 * 3; i += 256) {
            int loc = i / 3, cc = i - loc * 3;
            int node = base + loc;
            if (node < NN) {
                float4 v = *(const float4*)(x + (size_t)node * FIN + cc * 4);
                float sc = dl[loc];
                gA[(size_t)node * 3 + cc] =
                    make_uint2(pack2(v.x * sc, v.y * sc), pack2(v.z * sc, v.w * sc));
            }
        }
    }
}

// ---------------- diffusion gather ----------------
// bf16 rows (12 halves = 24B): random-read working set 2.4 MB/direction,
// fully resident in a 4 MB XCD L2. All arithmetic fp32; rounding only at
// stores. XCD direction split (0-3 fwd, 4-7 rev), rec2 LDS staging (R15),
// LREC=2048 (R16), 8-wide unrolled edge loop.
#define LREC 2048
__global__ __launch_bounds__(256) void k_gather(
        const int* __restrict__ off_node, const int* __restrict__ rec2,
        const uint2* __restrict__ gIn, const uint2* __restrict__ hIn,
        const uint2* __restrict__ prevF, const uint2* __restrict__ prevR,
        const float* __restrict__ dinv_in, const float* __restrict__ dinv_out,
        uint2* __restrict__ outF, uint2* __restrict__ outR,
        uint2* __restrict__ gOut, float c) {
    __shared__ int lrec[LREC];
    int xcd = blockIdx.x & 7;
    int grp = blockIdx.x >> 3;             // 0..292
    bool rev = xcd >= 4;
    int dbase = rev ? NN : 0;
    int ub = (grp * 4 + (xcd & 3)) * 256;  // block's first lin
    int lin = ub + threadIdx.x;

    // block's contiguous rec2 window
    int u1 = ub + 255; if (u1 > 3 * NN - 1) u1 = 3 * NN - 1;
    int node0 = ub / 3, node1 = u1 / 3;
    int w0 = off_node[dbase + node0];
    int w1 = off_node[dbase + node1 + 1];
    int wn = w1 - w0;
    bool useLds = (wn <= LREC);
    if (useLds) {
        for (int i = threadIdx.x; i < wn; i += 256) lrec[i] = rec2[w0 + i];
    }
    __syncthreads();

    if (lin < 3 * NN) {
        int node = lin / 3;
        int ch = lin - node * 3;
        int i0 = dbase + node;
        int e0 = off_node[i0], e1 = off_node[i0 + 1];
        const uint2* in = rev ? hIn : gIn;

        float ax = 0.f, ay = 0.f, az = 0.f, aw = 0.f;
        float bx = 0.f, by = 0.f, bz = 0.f, bw = 0.f;
        if (useLds) {
            int a0 = e0 - w0, a1 = e1 - w0;
            int e = a0;
            for (; e + 7 < a1; e += 8) {
                int n0 = lrec[e],     n1 = lrec[e + 1], n2 = lrec[e + 2], n3 = lrec[e + 3];
                int n4 = lrec[e + 4], n5 = lrec[e + 5], n6 = lrec[e + 6], n7 = lrec[e + 7];
                uint2 v0 = in[(size_t)n0 * 3 + ch];
                uint2 v1 = in[(size_t)n1 * 3 + ch];
                uint2 v2 = in[(size_t)n2 * 3 + ch];
                uint2 v3 = in[(size_t)n3 * 3 + ch];
                uint2 v4 = in[(size_t)n4 * 3 + ch];
                uint2 v5 = in[(size_t)n5 * 3 + ch];
                uint2 v6 = in[(size_t)n6 * 3 + ch];
                uint2 v7 = in[(size_t)n7 * 3 + ch];
                ax += BLO(v0.x); ay += BHI(v0.x); az += BLO(v0.y); aw += BHI(v0.y);
                bx += BLO(v1.x); by += BHI(v1.x); bz += BLO(v1.y); bw += BHI(v1.y);
                ax += BLO(v2.x); ay += BHI(v2.x); az += BLO(v2.y); aw += BHI(v2.y);
                bx += BLO(v3.x); by += BHI(v3.x); bz += BLO(v3.y); bw += BHI(v3.y);
                ax += BLO(v4.x); ay += BHI(v4.x); az += BLO(v4.y); aw += BHI(v4.y);
                bx += BLO(v5.x); by += BHI(v5.x); bz += BLO(v5.y); bw += BHI(v5.y);
                ax += BLO(v6.x); ay += BHI(v6.x); az += BLO(v6.y); aw += BHI(v6.y);
                bx += BLO(v7.x); by += BHI(v7.x); bz += BLO(v7.y); bw += BHI(v7.y);
            }
            for (; e < a1; ++e) {
                int n0 = lrec[e];
                uint2 v0 = in[(size_t)n0 * 3 + ch];
                ax += BLO(v0.x); ay += BHI(v0.x); az += BLO(v0.y); aw += BHI(v0.y);
            }
        } else {
            for (int e = e0; e < e1; ++e) {
                int n0 = rec2[e];
                uint2 v0 = in[(size_t)n0 * 3 + ch];
                ax += BLO(v0.x); ay += BHI(v0.x); az += BLO(v0.y); aw += BHI(v0.y);
            }
        }
        ax += bx; ay += by; az += bz; aw += bw;

        float sc = rev ? c * dinv_in[node] : c;
        ax *= sc; ay *= sc; az *= sc; aw *= sc;

        size_t o = (size_t)node * 3 + ch;
        if (prevF) {
            uint2 p = (rev ? prevR : prevF)[o];
            ax -= BLO(p.x); ay -= BHI(p.x); az -= BLO(p.y); aw -= BHI(p.y);
        }
        (rev ? outR : outF)[o] = make_uint2(pack2(ax, ay), pack2(az, aw));
        if (!rev && gOut) {
            float g = dinv_out[node];
            gOut[o] = make_uint2(pack2(g * ax, g * ay), pack2(g * az, g * aw));
        }
    }
}

// ---------------- epilogue ----------------

// Wave-level feature split + LDS row staging. TS rows are bf16 (unpacked to
// fp32 in LDS); block-0 x term stays exact fp32.
__global__ __launch_bounds__(256) void k_fused(
        const float* __restrict__ x, const uint2* __restrict__ TS2,
        const float* __restrict__ Wz, const float* __restrict__ Wh,
        const float* __restrict__ bz, const float* __restrict__ bh,
        const float* __restrict__ Wlin, float* __restrict__ out) {
    __shared__ float rows[128][13];
    __shared__ float red[256 * CC];
    int g = blockIdx.x >> 3;
    int seg = blockIdx.x & 7;
    int base = g * 1000 + seg * 125;
    int tid = threadIdx.x;
    int lane = tid & 63;
    int wave = tid >> 6;
    int f0 = __builtin_amdgcn_readfirstlane(wave * 8);   // wave-uniform f-quarter

    float az0[8], ah0[8], az1[8], ah1[8];
#pragma unroll
    for (int fi = 0; fi < 8; ++fi) {
        float vz = bz[f0 + fi], vh = bh[f0 + fi];
        az0[fi] = vz; ah0[fi] = vh; az1[fi] = vz; ah1[fi] = vh;
    }
    bool act1 = (lane + 64) < 125;     // second node valid for lanes 0..60

    for (int b = 0; b < 9; ++b) {
        __syncthreads();               // protect rows[] from prior-iter readers
        if (b == 0) {
            const float* src = x + (size_t)base * FIN;
            for (int q = tid; q < 375; q += 256) {    // 125*12 floats = 375 float4
                float4 v = *(const float4*)(src + q * 4);
                int e = q * 4;
                int n0 = e / 12,       i0 = e - n0 * 12;       rows[n0][i0] = v.x;
                int n1 = (e + 1) / 12, i1 = (e + 1) - n1 * 12; rows[n1][i1] = v.y;
                int n2 = (e + 2) / 12, i2 = (e + 2) - n2 * 12; rows[n2][i2] = v.z;
                int n3 = (e + 3) / 12, i3 = (e + 3) - n3 * 12; rows[n3][i3] = v.w;
            }
        } else {
            const uint2* Tb = TS2 + (size_t)(b - 1) * NN * 3;
            for (int q = tid; q < 375; q += 256) {    // 125 nodes x 3 chunks
                int n = q / 3, cc = q - n * 3;
                uint2 v = Tb[(size_t)(base + n) * 3 + cc];
                rows[n][cc * 4 + 0] = BLO(v.x);
                rows[n][cc * 4 + 1] = BHI(v.x);
                rows[n][cc * 4 + 2] = BLO(v.y);
                rows[n][cc * 4 + 3] = BHI(v.y);
            }
        }
        __syncthreads();
        const float* wzr = Wz + b * 12 * FOUT + f0;
        const float* whr = Wh + b * 12 * FOUT + f0;
#pragma unroll
        for (int i = 0; i < FIN; ++i) {
            float v0 = rows[lane][i];
            float v1 = rows[lane + 64][i];   // in-bounds (<=127); masked later
#pragma unroll
            for (int fi = 0; fi < 8; ++fi) {
                float wz = wzr[i * FOUT + fi];   // scalar loads (wave-uniform addr)
                float wh = whr[i * FOUT + fi];
                az0[fi] = fmaf(v0, wz, az0[fi]);
                az1[fi] = fmaf(v1, wz, az1[fi]);
                ah0[fi] = fmaf(v0, wh, ah0[fi]);
                ah1[fi] = fmaf(v1, wh, ah1[fi]);
            }
        }
    }

    float o[CC] = {0.f, 0.f, 0.f, 0.f};
#pragma unroll
    for (int fi = 0; fi < 8; ++fi) {
        float z = 1.f / (1.f + __expf(-az0[fi]));
        float e2 = __expf(2.f * ah0[fi]);
        float th = 1.f - 2.f / (e2 + 1.f);
        float hv = fmaxf((1.f - z) * th, 0.f);
#pragma unroll
        for (int c = 0; c < CC; ++c) o[c] = fmaf(hv, Wlin[(f0 + fi) * 4 + c], o[c]);
    }
    if (act1) {
#pragma unroll
        for (int fi = 0; fi < 8; ++fi) {
            float z = 1.f / (1.f + __expf(-az1[fi]));
            float e2 = __expf(2.f * ah1[fi]);
            float th = 1.f - 2.f / (e2 + 1.f);
            float hv = fmaxf((1.f - z) * th, 0.f);
#pragma unroll
            for (int c = 0; c < CC; ++c) o[c] = fmaf(hv, Wlin[(f0 + fi) * 4 + c], o[c]);
        }
    }

#pragma unroll
    for (int c = 0; c < CC; ++c) red[tid * CC + c] = o[c];
    __syncthreads();
    for (int st = 128; st > 0; st >>= 1) {
        if (tid < st) {
#pragma unroll
            for (int c = 0; c < CC; ++c) red[tid * CC + c] += red[(tid + st) * CC + c];
        }
        __syncthreads();
    }
    if (tid == 0) {
#pragma unroll
        for (int c = 0; c < CC; ++c) atomicAdd(out + g * CC + c, red[c] * 0.001f);
    }
}

// ---------------- launch ----------------

extern "C" void kernel_launch(void* const* d_in, const int* in_sizes, int n_in,
                              void* d_out, int out_size, void* d_ws, size_t ws_size,
                              hipStream_t stream) {
    const float* x     = (const float*)d_in[0];
    const int*   ei    = (const int*)d_in[1];
    const float* ew    = (const float*)d_in[2];
    // d_in[3] (batch) unused: graphs are exactly 1000 contiguous nodes
    const float* W_z   = (const float*)d_in[4];
    const float* b_z   = (const float*)d_in[5];
    // d_in[6], d_in[7] (W_r, b_r) unused: R only multiplies the zero hidden state
    const float* W_h   = (const float*)d_in[8];
    const float* b_h   = (const float*)d_in[9];
    const float* W_lin = (const float*)d_in[10];
    const float* b_lin = (const float*)d_in[11];
    float* out = (float*)d_out;

    // ---- workspace layout (~48 MB) ----
    // [rec2 12.8MB][TSb 19.2MB bf16 basis | recA 25.6MB spans TSb + 6.4MB pad]
    // [gA][gB][xb] bf16 2.4MB each, placed AFTER recA's span (k_subcsr writes
    // gA while recA is still live) [dinv][W][off][off_node]
    int*   rec2     = (int*)d_ws;                       // 2*EE ints
    unsigned* TSb   = (unsigned*)(rec2 + 2 * (size_t)EE);  // 8 * NN*6 uints (bf16 rows)
    int2*  recA     = (int2*)TSb;                       // ALIAS: 2*EE int2, dead before gather 1
    int*   hist_g   = rec2;                             // ALIAS: NSEG ints, dead before k_subcsr writes rec2
    int*   bsumS    = rec2 + NSEG;                      // ALIAS: 782 ints
    unsigned* gAu   = TSb + (size_t)8 * NN * 6 + 1600000;  // past recA span (pad 6.4MB)
    unsigned* gBu   = gAu + (size_t)NN * 6;
    unsigned* xbu   = gBu + (size_t)NN * 6;
    float* dinv_in  = (float*)(xbu + (size_t)NN * 6);   // N
    float* dinv_out = dinv_in + NN;                     // N
    float* Wz       = dinv_out + NN;                    // 108*32
    float* Wh       = Wz + ROWS * FOUT;                 // 108*32
    int*   off      = (int*)(Wh + ROWS * FOUT);         // NBINS+1
    int*   off_node = off + NBINS + 1;                  // 2N+1

    uint2* TS2 = (uint2*)TSb;
    uint2* T1o = TS2 + (size_t)0 * NN * 3;
    uint2* T2o = TS2 + (size_t)1 * NN * 3;
    uint2* T3o = TS2 + (size_t)2 * NN * 3;
    uint2* T4o = TS2 + (size_t)3 * NN * 3;
    uint2* T1i = TS2 + (size_t)4 * NN * 3;
    uint2* T2i = TS2 + (size_t)5 * NN * 3;
    uint2* T3i = TS2 + (size_t)6 * NN * 3;
    uint2* T4i = TS2 + (size_t)7 * NN * 3;
    uint2* gA = (uint2*)gAu;
    uint2* gB = (uint2*)gBu;
    uint2* xb = (uint2*)xbu;

    dim3 B(256);
    int nbG = 2344;                            // 293 * 8 — exact for the XCD swizzle
    int nbScan = NSEG / 1024;                  // 782, exact

    k_hist<<<NBC, 512, 0, stream>>>(ei, hist_g);
    k_scan1<<<nbScan, 1024, 0, stream>>>(hist_g, bsumS, W_z, W_h, Wz, Wh, b_lin, out, x, xb);
    k_scan3<<<nbScan, 1024, 0, stream>>>(hist_g, bsumS, off, off_node);
    k_place<<<NBC, 512, 0, stream>>>(ei, ew, hist_g, recA);
    k_subcsr<<<NBINS, B, 0, stream>>>(off, recA, x, off_node, rec2, dinv_in, dinv_out, gA);

    // Chebyshev diffusion basis (bf16 storage, fp32 math): per-node gather
    // (LDS-staged rec2), pre-scaled fwd inputs (gA/gB), xb = bf16 x.
    k_gather<<<nbG, B, 0, stream>>>(off_node, rec2, gA, xb,  nullptr, nullptr, dinv_in, dinv_out, T1o, T1i, gB, 1.f);
    k_gather<<<nbG, B, 0, stream>>>(off_node, rec2, gB, T1i, xb,      xb,      dinv_in, dinv_out, T2o, T2i, gA, 2.f);
    k_gather<<<nbG, B, 0, stream>>>(off_node, rec2, gA, T2i, T1o,     T1i,     dinv_in, dinv_out, T3o, T3i, gB, 2.f);
    k_gather<<<nbG, B, 0, stream>>>(off_node, rec2, gB, T3i, T2o,     T2i,     dinv_in, dinv_out, T4o, T4i, nullptr, 2.f);

    k_fused<<<8 * GG, B, 0, stream>>>(x, TS2, Wz, Wh, b_z, b_h, W_lin, out);
}

// Round 12
// 279.157 us; speedup vs baseline: 1.1731x; 1.0248x over previous
//
#include <hip/hip_runtime.h>
#include <math.h>

#define NN    100000
#define GG    100
#define FIN   12
#define FOUT  32
#define KD    5
#define CC    4
#define EE    1600000
#define ROWS  108          // 9 blocks * 12 features
#define NBF   782          // fwd coarse bins (128 nodes each; last has 96)
#define NBINS 1564         // fwd bins + rev bins
#define NBC   512          // chunks in the coarse build (CHUNK=3125, exact)
#define CHUNK 3125
#define TOTR  (2 * CHUNK)  // records staged per block in k_place
#define NSEG  (NBINS * NBC)   // 800768 = 782 * 1024 exactly
#define NBSCAN (NSEG / 1024)  // 782 scan blocks
#define SUBMAX 3072        // R20: k_subcsr LDS staging capacity (bin ~2048+4.5sd)

// bf16 helpers: RNE pack, shift unpack. Storage-only precision cut — all
// arithmetic stays fp32. Random-gather working set per direction 2.4 MB
// (< 4 MB per-XCD L2). Ledger: R19 (padded rows) REGRESSED; R21 (coop
// gather fusion) kills graph capture — BANNED; R22 (step-4 fold) neutral;
// R23 (small segments) REGRESSED; R24 (producer/consumer split) REGRESSED.
// R26: k_scan3 folded into k_place — each k_place block derives global
// bases from block-scanned g[] + an in-LDS bsum prefix; block 0 emits
// off[] and terminators. One fewer 800k-thread dispatch.
__device__ __forceinline__ unsigned bfr(float f) {
    unsigned u = __float_as_uint(f);
    return (u + 0x7FFFu + ((u >> 16) & 1u)) >> 16;
}
__device__ __forceinline__ unsigned pack2(float a, float b) {
    return bfr(a) | (bfr(b) << 16);
}
#define BLO(u) __uint_as_float((u) << 16)
#define BHI(u) __uint_as_float((u) & 0xFFFF0000u)

// XCD-contiguous chunk remap (R11: contiguous ei/ew reads per XCD).
__device__ __forceinline__ int chunk_of_block(int b) {
    return ((b & 7) << 6) | (b >> 3);      // NBC=512: xcd*64 + seq
}

// ---------------- coarse-bucket CSR build ----------------
// Bin layout: bin_f = dst>>7 in [0,NBF); bin_r = NBF + (src>>7).
// recA (bin-major): .x = nbr | (local_node << 17), .y = edge weight.
// R18: k_place LDS-stages its chunk's records bin-sorted, then streams them
// out with full-line coalesced stores (killed the 4.3x dirty-line-thrash
// write amplification).

// P1: per-block LDS histogram -> stores into bin-major hist_g[bin][chunk].
__global__ __launch_bounds__(512) void k_hist(const int* __restrict__ ei,
                                              int* __restrict__ hist_g) {
    __shared__ int hist[NBINS];
    for (int i = threadIdx.x; i < NBINS; i += 512) hist[i] = 0;
    __syncthreads();
    int chunk = chunk_of_block(blockIdx.x);
    int lo = chunk * CHUNK, hi = lo + CHUNK;
    for (int e = lo + threadIdx.x; e < hi; e += 512) {
        int s = ei[e], d = ei[EE + e];
        atomicAdd(&hist[d >> 7], 1);
        atomicAdd(&hist[NBF + (s >> 7)], 1);
    }
    __syncthreads();
    for (int i = threadIdx.x; i < NBINS; i += 512)
        hist_g[i * NBC + chunk] = hist[i];
}

// P2: block-wise exclusive scan of hist_g (g[i] -> block-local exclusive,
// bsum[blk] -> block total); ALSO absorbs the old k_misc (R20: weight
// collapse, out init, bf16-x build ride the 800k-thread grid for free).
// Global bases are reconstructed inside k_place (R26) — no scan3 pass.
__global__ __launch_bounds__(1024) void k_scan1(
        int* __restrict__ g, int* __restrict__ bsum,
        const float* __restrict__ Wz_in, const float* __restrict__ Wh_in,
        float* __restrict__ Wz, float* __restrict__ Wh,
        const float* __restrict__ b_lin, float* __restrict__ out,
        const float* __restrict__ x, uint2* __restrict__ xb) {
    __shared__ int sh[1024];
    int t = threadIdx.x;
    int i = blockIdx.x * 1024 + t;
    int v = g[i];                      // NSEG is an exact multiple of 1024
    sh[t] = v;
    __syncthreads();
    for (int d = 1; d < 1024; d <<= 1) {
        int x2 = sh[t];
        if (t >= d) x2 += sh[t - d];
        __syncthreads();
        sh[t] = x2;
        __syncthreads();
    }
    g[i] = sh[t] - v;
    if (t == 1023) bsum[blockIdx.x] = sh[1023];

    // ---- folded misc work (thread id i spans 0..800767) ----
    if (i < 2 * ROWS * FOUT) {
        int sel = i / (ROWS * FOUT);
        int rem = i - sel * ROWS * FOUT;
        int r = rem / FOUT;
        int f = rem - r * FOUT;
        int b = r / 12;
        int ii = r - b * 12;
        const float* Ws = sel ? Wh_in : Wz_in;
        float vv;
        if (b == 0)
            vv = Ws[(0 * KD + 0) * 44 * 32 + ii * 32 + f] + Ws[(1 * KD + 0) * 44 * 32 + ii * 32 + f];
        else if (b <= 4)
            vv = Ws[(0 * KD + b) * 44 * 32 + ii * 32 + f];
        else
            vv = Ws[(1 * KD + (b - 4)) * 44 * 32 + ii * 32 + f];
        (sel ? Wh : Wz)[r * FOUT + f] = vv;
    }
    int u = i - 2 * ROWS * FOUT;
    if (u >= 0 && u < GG * CC) out[u] = b_lin[u & 3];
    if (i < 3 * NN) {
        int n = i / 3, c = i - n * 3;
        float4 vf = *(const float4*)(x + (size_t)n * FIN + c * 4);
        xb[(size_t)n * 3 + c] = make_uint2(pack2(vf.x, vf.y), pack2(vf.z, vf.w));
    }
}

// P3 (R26: absorbs scan3): each block scans bsum (782 entries) in LDS,
// derives global per-(bin,chunk) bases as g[i] + pre[i>>10], LDS-stages its
// chunk's records bin-sorted, and streams them out contiguously. Block 0
// (chunk 0) additionally writes off[bin] = its own bases + terminators.
__global__ __launch_bounds__(512) void k_place(const int* __restrict__ ei,
                                               const float* __restrict__ ew,
                                               const int* __restrict__ g,
                                               const int* __restrict__ bsum,
                                               int2* __restrict__ recA,
                                               int* __restrict__ off,
                                               int* __restrict__ off_node) {
    __shared__ int2 ldsrec[TOTR];            // 50 KB
    __shared__ int  lofs[NBINS];             // 6.2 KB (exclusive prefix)
    __shared__ int  cur[NBINS];              // 6.2 KB
    __shared__ int  sbase[NBINS];            // 6.2 KB (global segment bases)
    __shared__ unsigned short binof[TOTR];   // 12.5 KB (bin of LDS slot)
    int* scr = (int*)binof;                  // 512-int scan scratch (aliased)
    int* pre = scr + 512;                    // 782-int bsum exclusive prefix
    int t = threadIdx.x;
    int chunk = chunk_of_block(blockIdx.x);

    // exclusive prefix of bsum[0..NBSCAN), 2 elems/thread (k_scan2 pattern)
    int a = (2 * t     < NBSCAN) ? bsum[2 * t]     : 0;
    int b = (2 * t + 1 < NBSCAN) ? bsum[2 * t + 1] : 0;
    int s2 = a + b;
    scr[t] = s2;
    __syncthreads();
    for (int d = 1; d < 512; d <<= 1) {
        int x = scr[t];
        if (t >= d) x += scr[t - d];
        __syncthreads();
        scr[t] = x;
        __syncthreads();
    }
    int basep = scr[t] - s2;
    if (2 * t < NBSCAN)     pre[2 * t]     = basep;
    if (2 * t + 1 < NBSCAN) pre[2 * t + 1] = basep + a;
    __syncthreads();

    // per-(bin,chunk) global bases + counts from block-scanned g[] + pre[]
    for (int bin = t; bin < NBINS; bin += 512) {
        int i0 = bin * NBC + chunk;
        int b0 = g[i0] + pre[i0 >> 10];
        int b1;
        if (bin == NBINS - 1 && chunk == NBC - 1) {
            b1 = 2 * EE;
        } else {
            int i1 = (chunk < NBC - 1) ? i0 + 1 : (bin + 1) * NBC;
            b1 = g[i1] + pre[i1 >> 10];
        }
        sbase[bin] = b0;
        lofs[bin] = b1 - b0;                 // count; scanned in place below
        cur[bin] = 0;
        if (chunk == 0) off[bin] = b0;       // only block 0 has chunk 0
    }
    if (blockIdx.x == 0 && t == 0) { off[NBINS] = 2 * EE; off_node[2 * NN] = 2 * EE; }
    __syncthreads();

    // exclusive scan of lofs over NBINS: 4 elems/thread + Hillis-Steele
    // (scr region reused; pre is dead from here on)
    int i0 = t * 4;
    int v0 = 0, v1 = 0, v2 = 0, v3 = 0;
    if (i0 + 0 < NBINS) v0 = lofs[i0];
    if (i0 + 1 < NBINS) v1 = lofs[i0 + 1];
    if (i0 + 2 < NBINS) v2 = lofs[i0 + 2];
    if (i0 + 3 < NBINS) v3 = lofs[i0 + 3];
    int s = v0 + v1 + v2 + v3;
    scr[t] = s;
    __syncthreads();
    for (int d = 1; d < 512; d <<= 1) {
        int x = scr[t];
        if (t >= d) x += scr[t - d];
        __syncthreads();
        scr[t] = x;
        __syncthreads();
    }
    int run = scr[t] - s;
    __syncthreads();                         // scr reads done before binof reuse
    if (i0 + 0 < NBINS) { lofs[i0]     = run; run += v0; }
    if (i0 + 1 < NBINS) { lofs[i0 + 1] = run; run += v1; }
    if (i0 + 2 < NBINS) { lofs[i0 + 2] = run; run += v2; }
    if (i0 + 3 < NBINS) { lofs[i0 + 3] = run; run += v3; }
    __syncthreads();

    // place records into LDS, bin-sorted
    int lo = chunk * CHUNK;
    for (int e = lo + t; e < lo + CHUNK; e += 512) {
        int s3 = ei[e], d3 = ei[EE + e];
        float w = ew[e];
        int bf = d3 >> 7;
        int pf = lofs[bf] + atomicAdd(&cur[bf], 1);
        ldsrec[pf] = make_int2(s3 | ((d3 & 127) << 17), __float_as_int(w));
        binof[pf] = (unsigned short)bf;
        int br = NBF + (s3 >> 7);
        int pr = lofs[br] + atomicAdd(&cur[br], 1);
        ldsrec[pr] = make_int2(d3 | ((s3 & 127) << 17), __float_as_int(w));
        binof[pr] = (unsigned short)br;
    }
    __syncthreads();

    // coalesced write-out: slot i -> recA[sbase[bin] + (i - lofs[bin])]
    for (int i = t; i < TOTR; i += 512) {
        int bb = binof[i];
        recA[sbase[bb] + (i - lofs[bb])] = ldsrec[i];
    }
}

// P4: per-bin counting sort by local node -> exact per-node CSR (4B records),
// fused weighted-degree sums -> dinv, and (rev bins) gA = bf16(dinv_out .* x).
// R20: single global read of the recA segment — staged in LDS (SUBMAX), the
// histogram rides the staging pass and the placement pass reads LDS.
__global__ __launch_bounds__(256) void k_subcsr(
        const int* __restrict__ off, const int2* __restrict__ recA,
        const float* __restrict__ x,
        int* __restrict__ off_node, int* __restrict__ rec2,
        float* __restrict__ dinv_in, float* __restrict__ dinv_out,
        uint2* __restrict__ gA) {
    __shared__ int2  seg[SUBMAX];    // 24 KB
    __shared__ int   hist[128];
    __shared__ int   lofs[128];
    __shared__ int   cur[128];
    __shared__ float wsum[128];
    __shared__ float dl[128];
    int b = blockIdx.x;
    int t = threadIdx.x;
    if (t < 128) { hist[t] = 0; wsum[t] = 0.f; }
    __syncthreads();
    int e0 = off[b], e1 = off[b + 1];
    int cnt = e1 - e0;
    bool stg = (cnt <= SUBMAX);
    if (stg) {
        for (int i = t; i < cnt; i += 256) {
            int2 r = recA[e0 + i];
            seg[i] = r;
            int loc = r.x >> 17;
            atomicAdd(&hist[loc], 1);
            atomicAdd(&wsum[loc], __int_as_float(r.y));
        }
    } else {
        for (int i = t; i < cnt; i += 256) {
            int2 r = recA[e0 + i];
            int loc = r.x >> 17;
            atomicAdd(&hist[loc], 1);
            atomicAdd(&wsum[loc], __int_as_float(r.y));
        }
    }
    __syncthreads();
    if (t < 128) lofs[t] = hist[t];
    __syncthreads();
    for (int d = 1; d < 128; d <<= 1) {
        int v = 0;
        if (t < 128 && t >= d) v = lofs[t - d];
        __syncthreads();
        if (t < 128) lofs[t] += v;
        __syncthreads();
    }
    bool rev = b >= NBF;
    int base = (rev ? b - NBF : b) * 128;
    if (t < 128) {
        int ex = lofs[t] - hist[t];      // exclusive
        lofs[t] = ex;
        cur[t] = 0;
        int node = base + t;
        if (node < NN) {
            off_node[(rev ? NN : 0) + node] = e0 + ex;
            float inv = 1.f / wsum[t];
            dl[t] = inv;
            if (rev) dinv_out[node] = inv;
            else     dinv_in[node]  = inv;
        }
    }
    __syncthreads();
    if (stg) {
        for (int i = t; i < cnt; i += 256) {
            int rx = seg[i].x;
            int loc = rx >> 17;
            int pos = e0 + lofs[loc] + atomicAdd(&cur[loc], 1);
            rec2[pos] = rx & 0x1FFFF;
        }
    } else {
        for (int i = t; i < cnt; i += 256) {
            int rx = recA[e0 + i].x;
            int loc = rx >> 17;
            int pos = e0 + lofs[loc] + atomicAdd(&cur[loc], 1);
            rec2[pos] = rx & 0x1FFFF;
        }
    }
    if (rev) {
        __syncthreads();
        for (int i = t; i < 128 * 3; i += 256) {
            int loc = i / 3, cc = i - loc * 3;
            int node = base + loc;
            if (node < NN) {
                float4 v = *(const float4*)(x + (size_t)node * FIN + cc * 4);
                float sc = dl[loc];
                gA[(size_t)node * 3 + cc] =
                    make_uint2(pack2(v.x * sc, v.y * sc), pack2(v.z * sc, v.w * sc));
            }
        }
    }
}

// ---------------- diffusion gather ----------------
// bf16 rows (12 halves = 24B): random-read working set 2.4 MB/direction,
// fully resident in a 4 MB XCD L2. All arithmetic fp32; rounding only at
// stores. XCD direction split (0-3 fwd, 4-7 rev), rec2 LDS staging (R15),
// LREC=2048 (R16), 8-wide unrolled edge loop.
#define LREC 2048
__global__ __launch_bounds__(256) void k_gather(
        const int* __restrict__ off_node, const int* __restrict__ rec2,
        const uint2* __restrict__ gIn, const uint2* __restrict__ hIn,
        const uint2* __restrict__ prevF, const uint2* __restrict__ prevR,
        const float* __restrict__ dinv_in, const float* __restrict__ dinv_out,
        uint2* __restrict__ outF, uint2* __restrict__ outR,
        uint2* __restrict__ gOut, float c) {
    __shared__ int lrec[LREC];
    int xcd = blockIdx.x & 7;
    int grp = blockIdx.x >> 3;             // 0..292
    bool rev = xcd >= 4;
    int dbase = rev ? NN : 0;
    int ub = (grp * 4 + (xcd & 3)) * 256;  // block's first lin
    int lin = ub + threadIdx.x;

    // block's contiguous rec2 window
    int u1 = ub + 255; if (u1 > 3 * NN - 1) u1 = 3 * NN - 1;
    int node0 = ub / 3, node1 = u1 / 3;
    int w0 = off_node[dbase + node0];
    int w1 = off_node[dbase + node1 + 1];
    int wn = w1 - w0;
    bool useLds = (wn <= LREC);
    if (useLds) {
        for (int i = threadIdx.x; i < wn; i += 256) lrec[i] = rec2[w0 + i];
    }
    __syncthreads();

    if (lin < 3 * NN) {
        int node = lin / 3;
        int ch = lin - node * 3;
        int i0 = dbase + node;
        int e0 = off_node[i0], e1 = off_node[i0 + 1];
        const uint2* in = rev ? hIn : gIn;

        float ax = 0.f, ay = 0.f, az = 0.f, aw = 0.f;
        float bx = 0.f, by = 0.f, bz = 0.f, bw = 0.f;
        if (useLds) {
            int a0 = e0 - w0, a1 = e1 - w0;
            int e = a0;
            for (; e + 7 < a1; e += 8) {
                int n0 = lrec[e],     n1 = lrec[e + 1], n2 = lrec[e + 2], n3 = lrec[e + 3];
                int n4 = lrec[e + 4], n5 = lrec[e + 5], n6 = lrec[e + 6], n7 = lrec[e + 7];
                uint2 v0 = in[(size_t)n0 * 3 + ch];
                uint2 v1 = in[(size_t)n1 * 3 + ch];
                uint2 v2 = in[(size_t)n2 * 3 + ch];
                uint2 v3 = in[(size_t)n3 * 3 + ch];
                uint2 v4 = in[(size_t)n4 * 3 + ch];
                uint2 v5 = in[(size_t)n5 * 3 + ch];
                uint2 v6 = in[(size_t)n6 * 3 + ch];
                uint2 v7 = in[(size_t)n7 * 3 + ch];
                ax += BLO(v0.x); ay += BHI(v0.x); az += BLO(v0.y); aw += BHI(v0.y);
                bx += BLO(v1.x); by += BHI(v1.x); bz += BLO(v1.y); bw += BHI(v1.y);
                ax += BLO(v2.x); ay += BHI(v2.x); az += BLO(v2.y); aw += BHI(v2.y);
                bx += BLO(v3.x); by += BHI(v3.x); bz += BLO(v3.y); bw += BHI(v3.y);
                ax += BLO(v4.x); ay += BHI(v4.x); az += BLO(v4.y); aw += BHI(v4.y);
                bx += BLO(v5.x); by += BHI(v5.x); bz += BLO(v5.y); bw += BHI(v5.y);
                ax += BLO(v6.x); ay += BHI(v6.x); az += BLO(v6.y); aw += BHI(v6.y);
                bx += BLO(v7.x); by += BHI(v7.x); bz += BLO(v7.y); bw += BHI(v7.y);
            }
            for (; e < a1; ++e) {
                int n0 = lrec[e];
                uint2 v0 = in[(size_t)n0 * 3 + ch];
                ax += BLO(v0.x); ay += BHI(v0.x); az += BLO(v0.y); aw += BHI(v0.y);
            }
        } else {
            for (int e = e0; e < e1; ++e) {
                int n0 = rec2[e];
                uint2 v0 = in[(size_t)n0 * 3 + ch];
                ax += BLO(v0.x); ay += BHI(v0.x); az += BLO(v0.y); aw += BHI(v0.y);
            }
        }
        ax += bx; ay += by; az += bz; aw += bw;

        float sc = rev ? c * dinv_in[node] : c;
        ax *= sc; ay *= sc; az *= sc; aw *= sc;

        size_t o = (size_t)node * 3 + ch;
        if (prevF) {
            uint2 p = (rev ? prevR : prevF)[o];
            ax -= BLO(p.x); ay -= BHI(p.x); az -= BLO(p.y); aw -= BHI(p.y);
        }
        (rev ? outR : outF)[o] = make_uint2(pack2(ax, ay), pack2(az, aw));
        if (!rev && gOut) {
            float g = dinv_out[node];
            gOut[o] = make_uint2(pack2(g * ax, g * ay), pack2(g * az, g * aw));
        }
    }
}

// ---------------- epilogue ----------------

// Wave-level feature split + LDS row staging. TS rows are bf16 (unpacked to
// fp32 in LDS); block-0 x term stays exact fp32.
__global__ __launch_bounds__(256) void k_fused(
        const float* __restrict__ x, const uint2* __restrict__ TS2,
        const float* __restrict__ Wz, const float* __restrict__ Wh,
        const float* __restrict__ bz, const float* __restrict__ bh,
        const float* __restrict__ Wlin, float* __restrict__ out) {
    __shared__ float rows[128][13];
    __shared__ float red[256 * CC];
    int g = blockIdx.x >> 3;
    int seg = blockIdx.x & 7;
    int base = g * 1000 + seg * 125;
    int tid = threadIdx.x;
    int lane = tid & 63;
    int wave = tid >> 6;
    int f0 = __builtin_amdgcn_readfirstlane(wave * 8);   // wave-uniform f-quarter

    float az0[8], ah0[8], az1[8], ah1[8];
#pragma unroll
    for (int fi = 0; fi < 8; ++fi) {
        float vz = bz[f0 + fi], vh = bh[f0 + fi];
        az0[fi] = vz; ah0[fi] = vh; az1[fi] = vz; ah1[fi] = vh;
    }
    bool act1 = (lane + 64) < 125;     // second node valid for lanes 0..60

    for (int b = 0; b < 9; ++b) {
        __syncthreads();               // protect rows[] from prior-iter readers
        if (b == 0) {
            const float* src = x + (size_t)base * FIN;
            for (int q = tid; q < 375; q += 256) {    // 125*12 floats = 375 float4
                float4 v = *(const float4*)(src + q * 4);
                int e = q * 4;
                int n0 = e / 12,       i0 = e - n0 * 12;       rows[n0][i0] = v.x;
                int n1 = (e + 1) / 12, i1 = (e + 1) - n1 * 12; rows[n1][i1] = v.y;
                int n2 = (e + 2) / 12, i2 = (e + 2) - n2 * 12; rows[n2][i2] = v.z;
                int n3 = (e + 3) / 12, i3 = (e + 3) - n3 * 12; rows[n3][i3] = v.w;
            }
        } else {
            const uint2* Tb = TS2 + (size_t)(b - 1) * NN * 3;
            for (int q = tid; q < 375; q += 256) {    // 125 nodes x 3 chunks
                int n = q / 3, cc = q - n * 3;
                uint2 v = Tb[(size_t)(base + n) * 3 + cc];
                rows[n][cc * 4 + 0] = BLO(v.x);
                rows[n][cc * 4 + 1] = BHI(v.x);
                rows[n][cc * 4 + 2] = BLO(v.y);
                rows[n][cc * 4 + 3] = BHI(v.y);
            }
        }
        __syncthreads();
        const float* wzr = Wz + b * 12 * FOUT + f0;
        const float* whr = Wh + b * 12 * FOUT + f0;
#pragma unroll
        for (int i = 0; i < FIN; ++i) {
            float v0 = rows[lane][i];
            float v1 = rows[lane + 64][i];   // in-bounds (<=127); masked later
#pragma unroll
            for (int fi = 0; fi < 8; ++fi) {
                float wz = wzr[i * FOUT + fi];   // scalar loads (wave-uniform addr)
                float wh = whr[i * FOUT + fi];
                az0[fi] = fmaf(v0, wz, az0[fi]);
                az1[fi] = fmaf(v1, wz, az1[fi]);
                ah0[fi] = fmaf(v0, wh, ah0[fi]);
                ah1[fi] = fmaf(v1, wh, ah1[fi]);
            }
        }
    }

    float o[CC] = {0.f, 0.f, 0.f, 0.f};
#pragma unroll
    for (int fi = 0; fi < 8; ++fi) {
        float z = 1.f / (1.f + __expf(-az0[fi]));
        float e2 = __expf(2.f * ah0[fi]);
        float th = 1.f - 2.f / (e2 + 1.f);
        float hv = fmaxf((1.f - z) * th, 0.f);
#pragma unroll
        for (int c = 0; c < CC; ++c) o[c] = fmaf(hv, Wlin[(f0 + fi) * 4 + c], o[c]);
    }
    if (act1) {
#pragma unroll
        for (int fi = 0; fi < 8; ++fi) {
            float z = 1.f / (1.f + __expf(-az1[fi]));
            float e2 = __expf(2.f * ah1[fi]);
            float th = 1.f - 2.f / (e2 + 1.f);
            float hv = fmaxf((1.f - z) * th, 0.f);
#pragma unroll
            for (int c = 0; c < CC; ++c) o[c] = fmaf(hv, Wlin[(f0 + fi) * 4 + c], o[c]);
        }
    }

#pragma unroll
    for (int c = 0; c < CC; ++c) red[tid * CC + c] = o[c];
    __syncthreads();
    for (int st = 128; st > 0; st >>= 1) {
        if (tid < st) {
#pragma unroll
            for (int c = 0; c < CC; ++c) red[tid * CC + c] += red[(tid + st) * CC + c];
        }
        __syncthreads();
    }
    if (tid == 0) {
#pragma unroll
        for (int c = 0; c < CC; ++c) atomicAdd(out + g * CC + c, red[c] * 0.001f);
    }
}

// ---------------- launch ----------------

extern "C" void kernel_launch(void* const* d_in, const int* in_sizes, int n_in,
                              void* d_out, int out_size, void* d_ws, size_t ws_size,
                              hipStream_t stream) {
    const float* x     = (const float*)d_in[0];
    const int*   ei    = (const int*)d_in[1];
    const float* ew    = (const float*)d_in[2];
    // d_in[3] (batch) unused: graphs are exactly 1000 contiguous nodes
    const float* W_z   = (const float*)d_in[4];
    const float* b_z   = (const float*)d_in[5];
    // d_in[6], d_in[7] (W_r, b_r) unused: R only multiplies the zero hidden state
    const float* W_h   = (const float*)d_in[8];
    const float* b_h   = (const float*)d_in[9];
    const float* W_lin = (const float*)d_in[10];
    const float* b_lin = (const float*)d_in[11];
    float* out = (float*)d_out;

    // ---- workspace layout (~48 MB) ----
    // [rec2 12.8MB][TSb 19.2MB bf16 basis | recA 25.6MB spans TSb + 6.4MB pad]
    // [gA][gB][xb] bf16 2.4MB each, placed AFTER recA's span (k_subcsr writes
    // gA while recA is still live) [dinv][W][off][off_node]
    int*   rec2     = (int*)d_ws;                       // 2*EE ints
    unsigned* TSb   = (unsigned*)(rec2 + 2 * (size_t)EE);  // 8 * NN*6 uints (bf16 rows)
    int2*  recA     = (int2*)TSb;                       // ALIAS: 2*EE int2, dead before gather 1
    int*   hist_g   = rec2;                             // ALIAS: NSEG ints, dead before k_subcsr writes rec2
    int*   bsumS    = rec2 + NSEG;                      // ALIAS: 782 ints
    unsigned* gAu   = TSb + (size_t)8 * NN * 6 + 1600000;  // past recA span (pad 6.4MB)
    unsigned* gBu   = gAu + (size_t)NN * 6;
    unsigned* xbu   = gBu + (size_t)NN * 6;
    float* dinv_in  = (float*)(xbu + (size_t)NN * 6);   // N
    float* dinv_out = dinv_in + NN;                     // N
    float* Wz       = dinv_out + NN;                    // 108*32
    float* Wh       = Wz + ROWS * FOUT;                 // 108*32
    int*   off      = (int*)(Wh + ROWS * FOUT);         // NBINS+1
    int*   off_node = off + NBINS + 1;                  // 2N+1

    uint2* TS2 = (uint2*)TSb;
    uint2* T1o = TS2 + (size_t)0 * NN * 3;
    uint2* T2o = TS2 + (size_t)1 * NN * 3;
    uint2* T3o = TS2 + (size_t)2 * NN * 3;
    uint2* T4o = TS2 + (size_t)3 * NN * 3;
    uint2* T1i = TS2 + (size_t)4 * NN * 3;
    uint2* T2i = TS2 + (size_t)5 * NN * 3;
    uint2* T3i = TS2 + (size_t)6 * NN * 3;
    uint2* T4i = TS2 + (size_t)7 * NN * 3;
    uint2* gA = (uint2*)gAu;
    uint2* gB = (uint2*)gBu;
    uint2* xb = (uint2*)xbu;

    dim3 B(256);
    int nbG = 2344;                            // 293 * 8 — exact for the XCD swizzle
    int nbScan = NSEG / 1024;                  // 782, exact

    k_hist<<<NBC, 512, 0, stream>>>(ei, hist_g);
    k_scan1<<<nbScan, 1024, 0, stream>>>(hist_g, bsumS, W_z, W_h, Wz, Wh, b_lin, out, x, xb);
    k_place<<<NBC, 512, 0, stream>>>(ei, ew, hist_g, bsumS, recA, off, off_node);
    k_subcsr<<<NBINS, B, 0, stream>>>(off, recA, x, off_node, rec2, dinv_in, dinv_out, gA);

    // Chebyshev diffusion basis (bf16 storage, fp32 math): per-node gather
    // (LDS-staged rec2), pre-scaled fwd inputs (gA/gB), xb = bf16 x.
    k_gather<<<nbG, B, 0, stream>>>(off_node, rec2, gA, xb,  nullptr, nullptr, dinv_in, dinv_out, T1o, T1i, gB, 1.f);
    k_gather<<<nbG, B, 0, stream>>>(off_node, rec2, gB, T1i, xb,      xb,      dinv_in, dinv_out, T2o, T2i, gA, 2.f);
    k_gather<<<nbG, B, 0, stream>>>(off_node, rec2, gA, T2i, T1o,     T1i,     dinv_in, dinv_out, T3o, T3i, gB, 2.f);
    k_gather<<<nbG, B, 0, stream>>>(off_node, rec2, gB, T3i, T2o,     T2i,     dinv_in, dinv_out, T4o, T4i, nullptr, 2.f);

    k_fused<<<8 * GG, B, 0, stream>>>(x, TS2, Wz, Wh, b_z, b_h, W_lin, out);
}

// Round 13
// 276.711 us; speedup vs baseline: 1.1835x; 1.0088x over previous
//
#include <hip/hip_runtime.h>
#include <math.h>

#define NN    100000
#define GG    100
#define FIN   12
#define FOUT  32
#define KD    5
#define CC    4
#define EE    1600000
#define ROWS  108          // 9 blocks * 12 features
#define NBF   782          // fwd coarse bins (128 nodes each; last has 96)
#define NBINS 1564         // fwd bins + rev bins
#define NBC   512          // chunks in the coarse build (CHUNK=3125, exact)
#define CHUNK 3125
#define TOTR  (2 * CHUNK)  // records staged per block in k_place
#define NSEG  (NBINS * NBC)   // 800768 = 782 * 1024 exactly
#define NBSCAN (NSEG / 1024)  // 782 scan blocks
#define SUBMAX 3072        // R20: k_subcsr LDS staging capacity (bin ~2048+4.5sd)

// bf16 helpers: RNE pack, shift unpack. Storage-only precision cut — all
// arithmetic stays fp32. Random-gather working set per direction 2.4 MB
// (< 4 MB per-XCD L2). Ledger: R19 (padded rows) REGRESSED; R21 (coop
// gather fusion) kills graph capture — BANNED; R22 (step-4 fold) neutral;
// R23 (small segments) REGRESSED; R24 (producer/consumer split) REGRESSED;
// R26 (scan3 folded into k_place) WIN — 279.2 us.
// R27: k_fused software-pipelined staging — tile b+1 loads issue into
// VGPRs before FMA(b); LDS write at next phase top. Phase = max(lat, FMA).
__device__ __forceinline__ unsigned bfr(float f) {
    unsigned u = __float_as_uint(f);
    return (u + 0x7FFFu + ((u >> 16) & 1u)) >> 16;
}
__device__ __forceinline__ unsigned pack2(float a, float b) {
    return bfr(a) | (bfr(b) << 16);
}
#define BLO(u) __uint_as_float((u) << 16)
#define BHI(u) __uint_as_float((u) & 0xFFFF0000u)

// XCD-contiguous chunk remap (R11: contiguous ei/ew reads per XCD).
__device__ __forceinline__ int chunk_of_block(int b) {
    return ((b & 7) << 6) | (b >> 3);      // NBC=512: xcd*64 + seq
}

// ---------------- coarse-bucket CSR build ----------------
// Bin layout: bin_f = dst>>7 in [0,NBF); bin_r = NBF + (src>>7).
// recA (bin-major): .x = nbr | (local_node << 17), .y = edge weight.
// R18: k_place LDS-stages its chunk's records bin-sorted, then streams them
// out with full-line coalesced stores (killed the 4.3x dirty-line-thrash
// write amplification).

// P1: per-block LDS histogram -> stores into bin-major hist_g[bin][chunk].
__global__ __launch_bounds__(512) void k_hist(const int* __restrict__ ei,
                                              int* __restrict__ hist_g) {
    __shared__ int hist[NBINS];
    for (int i = threadIdx.x; i < NBINS; i += 512) hist[i] = 0;
    __syncthreads();
    int chunk = chunk_of_block(blockIdx.x);
    int lo = chunk * CHUNK, hi = lo + CHUNK;
    for (int e = lo + threadIdx.x; e < hi; e += 512) {
        int s = ei[e], d = ei[EE + e];
        atomicAdd(&hist[d >> 7], 1);
        atomicAdd(&hist[NBF + (s >> 7)], 1);
    }
    __syncthreads();
    for (int i = threadIdx.x; i < NBINS; i += 512)
        hist_g[i * NBC + chunk] = hist[i];
}

// P2: block-wise exclusive scan of hist_g (g[i] -> block-local exclusive,
// bsum[blk] -> block total); ALSO absorbs the old k_misc (R20: weight
// collapse, out init, bf16-x build ride the 800k-thread grid for free).
// Global bases are reconstructed inside k_place (R26) — no scan3 pass.
__global__ __launch_bounds__(1024) void k_scan1(
        int* __restrict__ g, int* __restrict__ bsum,
        const float* __restrict__ Wz_in, const float* __restrict__ Wh_in,
        float* __restrict__ Wz, float* __restrict__ Wh,
        const float* __restrict__ b_lin, float* __restrict__ out,
        const float* __restrict__ x, uint2* __restrict__ xb) {
    __shared__ int sh[1024];
    int t = threadIdx.x;
    int i = blockIdx.x * 1024 + t;
    int v = g[i];                      // NSEG is an exact multiple of 1024
    sh[t] = v;
    __syncthreads();
    for (int d = 1; d < 1024; d <<= 1) {
        int x2 = sh[t];
        if (t >= d) x2 += sh[t - d];
        __syncthreads();
        sh[t] = x2;
        __syncthreads();
    }
    g[i] = sh[t] - v;
    if (t == 1023) bsum[blockIdx.x] = sh[1023];

    // ---- folded misc work (thread id i spans 0..800767) ----
    if (i < 2 * ROWS * FOUT) {
        int sel = i / (ROWS * FOUT);
        int rem = i - sel * ROWS * FOUT;
        int r = rem / FOUT;
        int f = rem - r * FOUT;
        int b = r / 12;
        int ii = r - b * 12;
        const float* Ws = sel ? Wh_in : Wz_in;
        float vv;
        if (b == 0)
            vv = Ws[(0 * KD + 0) * 44 * 32 + ii * 32 + f] + Ws[(1 * KD + 0) * 44 * 32 + ii * 32 + f];
        else if (b <= 4)
            vv = Ws[(0 * KD + b) * 44 * 32 + ii * 32 + f];
        else
            vv = Ws[(1 * KD + (b - 4)) * 44 * 32 + ii * 32 + f];
        (sel ? Wh : Wz)[r * FOUT + f] = vv;
    }
    int u = i - 2 * ROWS * FOUT;
    if (u >= 0 && u < GG * CC) out[u] = b_lin[u & 3];
    if (i < 3 * NN) {
        int n = i / 3, c = i - n * 3;
        float4 vf = *(const float4*)(x + (size_t)n * FIN + c * 4);
        xb[(size_t)n * 3 + c] = make_uint2(pack2(vf.x, vf.y), pack2(vf.z, vf.w));
    }
}

// P3 (R26: absorbs scan3): each block scans bsum (782 entries) in LDS,
// derives global per-(bin,chunk) bases as g[i] + pre[i>>10], LDS-stages its
// chunk's records bin-sorted, and streams them out contiguously. Block 0
// (chunk 0) additionally writes off[bin] = its own bases + terminators.
__global__ __launch_bounds__(512) void k_place(const int* __restrict__ ei,
                                               const float* __restrict__ ew,
                                               const int* __restrict__ g,
                                               const int* __restrict__ bsum,
                                               int2* __restrict__ recA,
                                               int* __restrict__ off,
                                               int* __restrict__ off_node) {
    __shared__ int2 ldsrec[TOTR];            // 50 KB
    __shared__ int  lofs[NBINS];             // 6.2 KB (exclusive prefix)
    __shared__ int  cur[NBINS];              // 6.2 KB
    __shared__ int  sbase[NBINS];            // 6.2 KB (global segment bases)
    __shared__ unsigned short binof[TOTR];   // 12.5 KB (bin of LDS slot)
    int* scr = (int*)binof;                  // 512-int scan scratch (aliased)
    int* pre = scr + 512;                    // 782-int bsum exclusive prefix
    int t = threadIdx.x;
    int chunk = chunk_of_block(blockIdx.x);

    // exclusive prefix of bsum[0..NBSCAN), 2 elems/thread (k_scan2 pattern)
    int a = (2 * t     < NBSCAN) ? bsum[2 * t]     : 0;
    int b = (2 * t + 1 < NBSCAN) ? bsum[2 * t + 1] : 0;
    int s2 = a + b;
    scr[t] = s2;
    __syncthreads();
    for (int d = 1; d < 512; d <<= 1) {
        int x = scr[t];
        if (t >= d) x += scr[t - d];
        __syncthreads();
        scr[t] = x;
        __syncthreads();
    }
    int basep = scr[t] - s2;
    if (2 * t < NBSCAN)     pre[2 * t]     = basep;
    if (2 * t + 1 < NBSCAN) pre[2 * t + 1] = basep + a;
    __syncthreads();

    // per-(bin,chunk) global bases + counts from block-scanned g[] + pre[]
    for (int bin = t; bin < NBINS; bin += 512) {
        int i0 = bin * NBC + chunk;
        int b0 = g[i0] + pre[i0 >> 10];
        int b1;
        if (bin == NBINS - 1 && chunk == NBC - 1) {
            b1 = 2 * EE;
        } else {
            int i1 = (chunk < NBC - 1) ? i0 + 1 : (bin + 1) * NBC;
            b1 = g[i1] + pre[i1 >> 10];
        }
        sbase[bin] = b0;
        lofs[bin] = b1 - b0;                 // count; scanned in place below
        cur[bin] = 0;
        if (chunk == 0) off[bin] = b0;       // only block 0 has chunk 0
    }
    if (blockIdx.x == 0 && t == 0) { off[NBINS] = 2 * EE; off_node[2 * NN] = 2 * EE; }
    __syncthreads();

    // exclusive scan of lofs over NBINS: 4 elems/thread + Hillis-Steele
    // (scr region reused; pre is dead from here on)
    int i0 = t * 4;
    int v0 = 0, v1 = 0, v2 = 0, v3 = 0;
    if (i0 + 0 < NBINS) v0 = lofs[i0];
    if (i0 + 1 < NBINS) v1 = lofs[i0 + 1];
    if (i0 + 2 < NBINS) v2 = lofs[i0 + 2];
    if (i0 + 3 < NBINS) v3 = lofs[i0 + 3];
    int s = v0 + v1 + v2 + v3;
    scr[t] = s;
    __syncthreads();
    for (int d = 1; d < 512; d <<= 1) {
        int x = scr[t];
        if (t >= d) x += scr[t - d];
        __syncthreads();
        scr[t] = x;
        __syncthreads();
    }
    int run = scr[t] - s;
    __syncthreads();                         // scr reads done before binof reuse
    if (i0 + 0 < NBINS) { lofs[i0]     = run; run += v0; }
    if (i0 + 1 < NBINS) { lofs[i0 + 1] = run; run += v1; }
    if (i0 + 2 < NBINS) { lofs[i0 + 2] = run; run += v2; }
    if (i0 + 3 < NBINS) { lofs[i0 + 3] = run; run += v3; }
    __syncthreads();

    // place records into LDS, bin-sorted
    int lo = chunk * CHUNK;
    for (int e = lo + t; e < lo + CHUNK; e += 512) {
        int s3 = ei[e], d3 = ei[EE + e];
        float w = ew[e];
        int bf = d3 >> 7;
        int pf = lofs[bf] + atomicAdd(&cur[bf], 1);
        ldsrec[pf] = make_int2(s3 | ((d3 & 127) << 17), __float_as_int(w));
        binof[pf] = (unsigned short)bf;
        int br = NBF + (s3 >> 7);
        int pr = lofs[br] + atomicAdd(&cur[br], 1);
        ldsrec[pr] = make_int2(d3 | ((s3 & 127) << 17), __float_as_int(w));
        binof[pr] = (unsigned short)br;
    }
    __syncthreads();

    // coalesced write-out: slot i -> recA[sbase[bin] + (i - lofs[bin])]
    for (int i = t; i < TOTR; i += 512) {
        int bb = binof[i];
        recA[sbase[bb] + (i - lofs[bb])] = ldsrec[i];
    }
}

// P4: per-bin counting sort by local node -> exact per-node CSR (4B records),
// fused weighted-degree sums -> dinv, and (rev bins) gA = bf16(dinv_out .* x).
// R20: single global read of the recA segment — staged in LDS (SUBMAX), the
// histogram rides the staging pass and the placement pass reads LDS.
__global__ __launch_bounds__(256) void k_subcsr(
        const int* __restrict__ off, const int2* __restrict__ recA,
        const float* __restrict__ x,
        int* __restrict__ off_node, int* __restrict__ rec2,
        float* __restrict__ dinv_in, float* __restrict__ dinv_out,
        uint2* __restrict__ gA) {
    __shared__ int2  seg[SUBMAX];    // 24 KB
    __shared__ int   hist[128];
    __shared__ int   lofs[128];
    __shared__ int   cur[128];
    __shared__ float wsum[128];
    __shared__ float dl[128];
    int b = blockIdx.x;
    int t = threadIdx.x;
    if (t < 128) { hist[t] = 0; wsum[t] = 0.f; }
    __syncthreads();
    int e0 = off[b], e1 = off[b + 1];
    int cnt = e1 - e0;
    bool stg = (cnt <= SUBMAX);
    if (stg) {
        for (int i = t; i < cnt; i += 256) {
            int2 r = recA[e0 + i];
            seg[i] = r;
            int loc = r.x >> 17;
            atomicAdd(&hist[loc], 1);
            atomicAdd(&wsum[loc], __int_as_float(r.y));
        }
    } else {
        for (int i = t; i < cnt; i += 256) {
            int2 r = recA[e0 + i];
            int loc = r.x >> 17;
            atomicAdd(&hist[loc], 1);
            atomicAdd(&wsum[loc], __int_as_float(r.y));
        }
    }
    __syncthreads();
    if (t < 128) lofs[t] = hist[t];
    __syncthreads();
    for (int d = 1; d < 128; d <<= 1) {
        int v = 0;
        if (t < 128 && t >= d) v = lofs[t - d];
        __syncthreads();
        if (t < 128) lofs[t] += v;
        __syncthreads();
    }
    bool rev = b >= NBF;
    int base = (rev ? b - NBF : b) * 128;
    if (t < 128) {
        int ex = lofs[t] - hist[t];      // exclusive
        lofs[t] = ex;
        cur[t] = 0;
        int node = base + t;
        if (node < NN) {
            off_node[(rev ? NN : 0) + node] = e0 + ex;
            float inv = 1.f / wsum[t];
            dl[t] = inv;
            if (rev) dinv_out[node] = inv;
            else     dinv_in[node]  = inv;
        }
    }
    __syncthreads();
    if (stg) {
        for (int i = t; i < cnt; i += 256) {
            int rx = seg[i].x;
            int loc = rx >> 17;
            int pos = e0 + lofs[loc] + atomicAdd(&cur[loc], 1);
            rec2[pos] = rx & 0x1FFFF;
        }
    } else {
        for (int i = t; i < cnt; i += 256) {
            int rx = recA[e0 + i].x;
            int loc = rx >> 17;
            int pos = e0 + lofs[loc] + atomicAdd(&cur[loc], 1);
            rec2[pos] = rx & 0x1FFFF;
        }
    }
    if (rev) {
        __syncthreads();
        for (int i = t; i < 128 * 3; i += 256) {
            int loc = i / 3, cc = i - loc * 3;
            int node = base + loc;
            if (node < NN) {
                float4 v = *(const float4*)(x + (size_t)node * FIN + cc * 4);
                float sc = dl[loc];
                gA[(size_t)node * 3 + cc] =
                    make_uint2(pack2(v.x * sc, v.y * sc), pack2(v.z * sc, v.w * sc));
            }
        }
    }
}

// ---------------- diffusion gather ----------------
// bf16 rows (12 halves = 24B): random-read working set 2.4 MB/direction,
// fully resident in a 4 MB XCD L2. All arithmetic fp32; rounding only at
// stores. XCD direction split (0-3 fwd, 4-7 rev), rec2 LDS staging (R15),
// LREC=2048 (R16), 8-wide unrolled edge loop.
#define LREC 2048
__global__ __launch_bounds__(256) void k_gather(
        const int* __restrict__ off_node, const int* __restrict__ rec2,
        const uint2* __restrict__ gIn, const uint2* __restrict__ hIn,
        const uint2* __restrict__ prevF, const uint2* __restrict__ prevR,
        const float* __restrict__ dinv_in, const float* __restrict__ dinv_out,
        uint2* __restrict__ outF, uint2* __restrict__ outR,
        uint2* __restrict__ gOut, float c) {
    __shared__ int lrec[LREC];
    int xcd = blockIdx.x & 7;
    int grp = blockIdx.x >> 3;             // 0..292
    bool rev = xcd >= 4;
    int dbase = rev ? NN : 0;
    int ub = (grp * 4 + (xcd & 3)) * 256;  // block's first lin
    int lin = ub + threadIdx.x;

    // block's contiguous rec2 window
    int u1 = ub + 255; if (u1 > 3 * NN - 1) u1 = 3 * NN - 1;
    int node0 = ub / 3, node1 = u1 / 3;
    int w0 = off_node[dbase + node0];
    int w1 = off_node[dbase + node1 + 1];
    int wn = w1 - w0;
    bool useLds = (wn <= LREC);
    if (useLds) {
        for (int i = threadIdx.x; i < wn; i += 256) lrec[i] = rec2[w0 + i];
    }
    __syncthreads();

    if (lin < 3 * NN) {
        int node = lin / 3;
        int ch = lin - node * 3;
        int i0 = dbase + node;
        int e0 = off_node[i0], e1 = off_node[i0 + 1];
        const uint2* in = rev ? hIn : gIn;

        float ax = 0.f, ay = 0.f, az = 0.f, aw = 0.f;
        float bx = 0.f, by = 0.f, bz = 0.f, bw = 0.f;
        if (useLds) {
            int a0 = e0 - w0, a1 = e1 - w0;
            int e = a0;
            for (; e + 7 < a1; e += 8) {
                int n0 = lrec[e],     n1 = lrec[e + 1], n2 = lrec[e + 2], n3 = lrec[e + 3];
                int n4 = lrec[e + 4], n5 = lrec[e + 5], n6 = lrec[e + 6], n7 = lrec[e + 7];
                uint2 v0 = in[(size_t)n0 * 3 + ch];
                uint2 v1 = in[(size_t)n1 * 3 + ch];
                uint2 v2 = in[(size_t)n2 * 3 + ch];
                uint2 v3 = in[(size_t)n3 * 3 + ch];
                uint2 v4 = in[(size_t)n4 * 3 + ch];
                uint2 v5 = in[(size_t)n5 * 3 + ch];
                uint2 v6 = in[(size_t)n6 * 3 + ch];
                uint2 v7 = in[(size_t)n7 * 3 + ch];
                ax += BLO(v0.x); ay += BHI(v0.x); az += BLO(v0.y); aw += BHI(v0.y);
                bx += BLO(v1.x); by += BHI(v1.x); bz += BLO(v1.y); bw += BHI(v1.y);
                ax += BLO(v2.x); ay += BHI(v2.x); az += BLO(v2.y); aw += BHI(v2.y);
                bx += BLO(v3.x); by += BHI(v3.x); bz += BLO(v3.y); bw += BHI(v3.y);
                ax += BLO(v4.x); ay += BHI(v4.x); az += BLO(v4.y); aw += BHI(v4.y);
                bx += BLO(v5.x); by += BHI(v5.x); bz += BLO(v5.y); bw += BHI(v5.y);
                ax += BLO(v6.x); ay += BHI(v6.x); az += BLO(v6.y); aw += BHI(v6.y);
                bx += BLO(v7.x); by += BHI(v7.x); bz += BLO(v7.y); bw += BHI(v7.y);
            }
            for (; e < a1; ++e) {
                int n0 = lrec[e];
                uint2 v0 = in[(size_t)n0 * 3 + ch];
                ax += BLO(v0.x); ay += BHI(v0.x); az += BLO(v0.y); aw += BHI(v0.y);
            }
        } else {
            for (int e = e0; e < e1; ++e) {
                int n0 = rec2[e];
                uint2 v0 = in[(size_t)n0 * 3 + ch];
                ax += BLO(v0.x); ay += BHI(v0.x); az += BLO(v0.y); aw += BHI(v0.y);
            }
        }
        ax += bx; ay += by; az += bz; aw += bw;

        float sc = rev ? c * dinv_in[node] : c;
        ax *= sc; ay *= sc; az *= sc; aw *= sc;

        size_t o = (size_t)node * 3 + ch;
        if (prevF) {
            uint2 p = (rev ? prevR : prevF)[o];
            ax -= BLO(p.x); ay -= BHI(p.x); az -= BLO(p.y); aw -= BHI(p.y);
        }
        (rev ? outR : outF)[o] = make_uint2(pack2(ax, ay), pack2(az, aw));
        if (!rev && gOut) {
            float g = dinv_out[node];
            gOut[o] = make_uint2(pack2(g * ax, g * ay), pack2(g * az, g * aw));
        }
    }
}

// ---------------- epilogue ----------------

// Wave-level feature split + LDS row staging. TS rows are bf16 (unpacked to
// fp32 in LDS); block-0 x term stays exact fp32. R27: software-pipelined
// staging — each thread's <=2 loads for tile b+1 issue into VGPRs BEFORE
// the FMA over tile b; the LDS write happens at the next phase top. Load
// latency hides under ~384 FMA instructions; rows[] stays single-buffered
// (regs carry the data across the barrier).
__global__ __launch_bounds__(256) void k_fused(
        const float* __restrict__ x, const uint2* __restrict__ TS2,
        const float* __restrict__ Wz, const float* __restrict__ Wh,
        const float* __restrict__ bz, const float* __restrict__ bh,
        const float* __restrict__ Wlin, float* __restrict__ out) {
    __shared__ float rows[128][13];
    __shared__ float red[256 * CC];
    int g = blockIdx.x >> 3;
    int seg = blockIdx.x & 7;
    int base = g * 1000 + seg * 125;
    int tid = threadIdx.x;
    int lane = tid & 63;
    int wave = tid >> 6;
    int f0 = __builtin_amdgcn_readfirstlane(wave * 8);   // wave-uniform f-quarter

    float az0[8], ah0[8], az1[8], ah1[8];
#pragma unroll
    for (int fi = 0; fi < 8; ++fi) {
        float vz = bz[f0 + fi], vh = bh[f0 + fi];
        az0[fi] = vz; ah0[fi] = vh; az1[fi] = vz; ah1[fi] = vh;
    }
    bool act1 = (lane + 64) < 125;     // second node valid for lanes 0..60

    // per-thread staging items: q0 = tid (always < 375), q1 = tid+256 (< 375
    // iff tid < 119). Same coverage as the old 375-item strided loop.
    int q0 = tid, q1 = tid + 256;
    bool h1 = (q1 < 375);
    int n0q = q0 / 3, c0q = q0 - n0q * 3;
    int n1q = q1 / 3, c1q = q1 - n1q * 3;

    // prologue: issue tile-0 (x, fp32 float4) loads into regs
    const float* src = x + (size_t)base * FIN;
    float4 px0 = *(const float4*)(src + q0 * 4);
    float4 px1 = h1 ? *(const float4*)(src + q1 * 4) : make_float4(0.f, 0.f, 0.f, 0.f);
    uint2 pu0, pu1;

    for (int b = 0; b < 9; ++b) {
        __syncthreads();               // prior-iter readers of rows[] done
        if (b == 0) {
            // write tile 0 from float4 regs (element scatter, exact fp32)
            {
                int e = q0 * 4;
                int a0 = e / 12,       i0 = e - a0 * 12;       rows[a0][i0] = px0.x;
                int a1 = (e + 1) / 12, i1 = (e + 1) - a1 * 12; rows[a1][i1] = px0.y;
                int a2 = (e + 2) / 12, i2 = (e + 2) - a2 * 12; rows[a2][i2] = px0.z;
                int a3 = (e + 3) / 12, i3 = (e + 3) - a3 * 12; rows[a3][i3] = px0.w;
            }
            if (h1) {
                int e = q1 * 4;
                int a0 = e / 12,       i0 = e - a0 * 12;       rows[a0][i0] = px1.x;
                int a1 = (e + 1) / 12, i1 = (e + 1) - a1 * 12; rows[a1][i1] = px1.y;
                int a2 = (e + 2) / 12, i2 = (e + 2) - a2 * 12; rows[a2][i2] = px1.z;
                int a3 = (e + 3) / 12, i3 = (e + 3) - a3 * 12; rows[a3][i3] = px1.w;
            }
        } else {
            // write tile b from uint2 regs (bf16 unpack)
            rows[n0q][c0q * 4 + 0] = BLO(pu0.x);
            rows[n0q][c0q * 4 + 1] = BHI(pu0.x);
            rows[n0q][c0q * 4 + 2] = BLO(pu0.y);
            rows[n0q][c0q * 4 + 3] = BHI(pu0.y);
            if (h1) {
                rows[n1q][c1q * 4 + 0] = BLO(pu1.x);
                rows[n1q][c1q * 4 + 1] = BHI(pu1.x);
                rows[n1q][c1q * 4 + 2] = BLO(pu1.y);
                rows[n1q][c1q * 4 + 3] = BHI(pu1.y);
            }
        }
        // issue tile b+1 loads (T array index b) — land during FMA below
        if (b < 8) {
            const uint2* Tb = TS2 + (size_t)b * NN * 3;
            pu0 = Tb[(size_t)(base + n0q) * 3 + c0q];
            if (h1) pu1 = Tb[(size_t)(base + n1q) * 3 + c1q];
        }
        __syncthreads();               // rows[] ready
        const float* wzr = Wz + b * 12 * FOUT + f0;
        const float* whr = Wh + b * 12 * FOUT + f0;
#pragma unroll
        for (int i = 0; i < FIN; ++i) {
            float v0 = rows[lane][i];
            float v1 = rows[lane + 64][i];   // in-bounds (<=127); masked later
#pragma unroll
            for (int fi = 0; fi < 8; ++fi) {
                float wz = wzr[i * FOUT + fi];   // scalar loads (wave-uniform addr)
                float wh = whr[i * FOUT + fi];
                az0[fi] = fmaf(v0, wz, az0[fi]);
                az1[fi] = fmaf(v1, wz, az1[fi]);
                ah0[fi] = fmaf(v0, wh, ah0[fi]);
                ah1[fi] = fmaf(v1, wh, ah1[fi]);
            }
        }
    }

    float o[CC] = {0.f, 0.f, 0.f, 0.f};
#pragma unroll
    for (int fi = 0; fi < 8; ++fi) {
        float z = 1.f / (1.f + __expf(-az0[fi]));
        float e2 = __expf(2.f * ah0[fi]);
        float th = 1.f - 2.f / (e2 + 1.f);
        float hv = fmaxf((1.f - z) * th, 0.f);
#pragma unroll
        for (int c = 0; c < CC; ++c) o[c] = fmaf(hv, Wlin[(f0 + fi) * 4 + c], o[c]);
    }
    if (act1) {
#pragma unroll
        for (int fi = 0; fi < 8; ++fi) {
            float z = 1.f / (1.f + __expf(-az1[fi]));
            float e2 = __expf(2.f * ah1[fi]);
            float th = 1.f - 2.f / (e2 + 1.f);
            float hv = fmaxf((1.f - z) * th, 0.f);
#pragma unroll
            for (int c = 0; c < CC; ++c) o[c] = fmaf(hv, Wlin[(f0 + fi) * 4 + c], o[c]);
        }
    }

#pragma unroll
    for (int c = 0; c < CC; ++c) red[tid * CC + c] = o[c];
    __syncthreads();
    for (int st = 128; st > 0; st >>= 1) {
        if (tid < st) {
#pragma unroll
            for (int c = 0; c < CC; ++c) red[tid * CC + c] += red[(tid + st) * CC + c];
        }
        __syncthreads();
    }
    if (tid == 0) {
#pragma unroll
        for (int c = 0; c < CC; ++c) atomicAdd(out + g * CC + c, red[c] * 0.001f);
    }
}

// ---------------- launch ----------------

extern "C" void kernel_launch(void* const* d_in, const int* in_sizes, int n_in,
                              void* d_out, int out_size, void* d_ws, size_t ws_size,
                              hipStream_t stream) {
    const float* x     = (const float*)d_in[0];
    const int*   ei    = (const int*)d_in[1];
    const float* ew    = (const float*)d_in[2];
    // d_in[3] (batch) unused: graphs are exactly 1000 contiguous nodes
    const float* W_z   = (const float*)d_in[4];
    const float* b_z   = (const float*)d_in[5];
    // d_in[6], d_in[7] (W_r, b_r) unused: R only multiplies the zero hidden state
    const float* W_h   = (const float*)d_in[8];
    const float* b_h   = (const float*)d_in[9];
    const float* W_lin = (const float*)d_in[10];
    const float* b_lin = (const float*)d_in[11];
    float* out = (float*)d_out;

    // ---- workspace layout (~48 MB) ----
    // [rec2 12.8MB][TSb 19.2MB bf16 basis | recA 25.6MB spans TSb + 6.4MB pad]
    // [gA][gB][xb] bf16 2.4MB each, placed AFTER recA's span (k_subcsr writes
    // gA while recA is still live) [dinv][W][off][off_node]
    int*   rec2     = (int*)d_ws;                       // 2*EE ints
    unsigned* TSb   = (unsigned*)(rec2 + 2 * (size_t)EE);  // 8 * NN*6 uints (bf16 rows)
    int2*  recA     = (int2*)TSb;                       // ALIAS: 2*EE int2, dead before gather 1
    int*   hist_g   = rec2;                             // ALIAS: NSEG ints, dead before k_subcsr writes rec2
    int*   bsumS    = rec2 + NSEG;                      // ALIAS: 782 ints
    unsigned* gAu   = TSb + (size_t)8 * NN * 6 + 1600000;  // past recA span (pad 6.4MB)
    unsigned* gBu   = gAu + (size_t)NN * 6;
    unsigned* xbu   = gBu + (size_t)NN * 6;
    float* dinv_in  = (float*)(xbu + (size_t)NN * 6);   // N
    float* dinv_out = dinv_in + NN;                     // N
    float* Wz       = dinv_out + NN;                    // 108*32
    float* Wh       = Wz + ROWS * FOUT;                 // 108*32
    int*   off      = (int*)(Wh + ROWS * FOUT);         // NBINS+1
    int*   off_node = off + NBINS + 1;                  // 2N+1

    uint2* TS2 = (uint2*)TSb;
    uint2* T1o = TS2 + (size_t)0 * NN * 3;
    uint2* T2o = TS2 + (size_t)1 * NN * 3;
    uint2* T3o = TS2 + (size_t)2 * NN * 3;
    uint2* T4o = TS2 + (size_t)3 * NN * 3;
    uint2* T1i = TS2 + (size_t)4 * NN * 3;
    uint2* T2i = TS2 + (size_t)5 * NN * 3;
    uint2* T3i = TS2 + (size_t)6 * NN * 3;
    uint2* T4i = TS2 + (size_t)7 * NN * 3;
    uint2* gA = (uint2*)gAu;
    uint2* gB = (uint2*)gBu;
    uint2* xb = (uint2*)xbu;

    dim3 B(256);
    int nbG = 2344;                            // 293 * 8 — exact for the XCD swizzle
    int nbScan = NSEG / 1024;                  // 782, exact

    k_hist<<<NBC, 512, 0, stream>>>(ei, hist_g);
    k_scan1<<<nbScan, 1024, 0, stream>>>(hist_g, bsumS, W_z, W_h, Wz, Wh, b_lin, out, x, xb);
    k_place<<<NBC, 512, 0, stream>>>(ei, ew, hist_g, bsumS, recA, off, off_node);
    k_subcsr<<<NBINS, B, 0, stream>>>(off, recA, x, off_node, rec2, dinv_in, dinv_out, gA);

    // Chebyshev diffusion basis (bf16 storage, fp32 math): per-node gather
    // (LDS-staged rec2), pre-scaled fwd inputs (gA/gB), xb = bf16 x.
    k_gather<<<nbG, B, 0, stream>>>(off_node, rec2, gA, xb,  nullptr, nullptr, dinv_in, dinv_out, T1o, T1i, gB, 1.f);
    k_gather<<<nbG, B, 0, stream>>>(off_node, rec2, gB, T1i, xb,      xb,      dinv_in, dinv_out, T2o, T2i, gA, 2.f);
    k_gather<<<nbG, B, 0, stream>>>(off_node, rec2, gA, T2i, T1o,     T1i,     dinv_in, dinv_out, T3o, T3i, gB, 2.f);
    k_gather<<<nbG, B, 0, stream>>>(off_node, rec2, gB, T3i, T2o,     T2i,     dinv_in, dinv_out, T4o, T4i, nullptr, 2.f);

    k_fused<<<8 * GG, B, 0, stream>>>(x, TS2, Wz, Wh, b_z, b_h, W_lin, out);
}